// Round 7
// baseline (298.898 us; speedup 1.0000x reference)
//
#include <hip/hip_runtime.h>

// Problem constants: B=4, S=2048, D=1024, H=16, HD=64
#define S_LEN 2048
#define NH 16
#define HDIM 64
#define DMODEL 1024

typedef __attribute__((ext_vector_type(8))) short bf16x8;
typedef __attribute__((ext_vector_type(4))) float f32x4;

__device__ __forceinline__ short f2bf(float f) {
    union { float f; unsigned u; } x; x.f = f;
    unsigned r = x.u + 0x7fffu + ((x.u >> 16) & 1u);  // round-to-nearest-even
    return (short)(r >> 16);
}

#define GLDS(g, l) __builtin_amdgcn_global_load_lds( \
    (__attribute__((address_space(1))) void*)(g),    \
    (__attribute__((address_space(3))) void*)(l), 16, 0, 0)

#define QSCALE 0.18033688011112042f   // 0.125 * log2(e)
#define FREQ_L 0.41524101186109327f   // log2(10000)/32

// ---------------------------------------------------------------- prep (one launch)
// blocks [0,8192):      cast x (f32 -> bf16)
// blocks [8192,12288):  cast Wq/Wk/Wv/Wo
// blocks [12288,13312): RoPE cos/sin table [B][S][32] float2
__global__ __launch_bounds__(256) void prep(const float* __restrict__ x,
                                            const float* __restrict__ wq,
                                            const float* __restrict__ wk,
                                            const float* __restrict__ wv,
                                            const float* __restrict__ wo,
                                            const int* __restrict__ tp,
                                            short* __restrict__ xb,
                                            short* __restrict__ wqb,
                                            short* __restrict__ wkb,
                                            short* __restrict__ wvb,
                                            short* __restrict__ wob,
                                            float2* __restrict__ tab) {
    int bid = blockIdx.x;
    if (bid < 8192) {
        int i = bid * 256 + threadIdx.x;
        float4 v = ((const float4*)x)[i];
        short4 o;
        o.x = f2bf(v.x); o.y = f2bf(v.y); o.z = f2bf(v.z); o.w = f2bf(v.w);
        ((short4*)xb)[i] = o;
    } else if (bid < 12288) {
        int sel = (bid - 8192) >> 10;
        const float* in = sel == 0 ? wq : sel == 1 ? wk : sel == 2 ? wv : wo;
        short* out = sel == 0 ? wqb : sel == 1 ? wkb : sel == 2 ? wvb : wob;
        int i = ((bid - 8192) & 1023) * 256 + threadIdx.x;
        float4 v = ((const float4*)in)[i];
        short4 o;
        o.x = f2bf(v.x); o.y = f2bf(v.y); o.z = f2bf(v.z); o.w = f2bf(v.w);
        ((short4*)out)[i] = o;
    } else {
        int idx = (bid - 12288) * 256 + threadIdx.x;   // < 262144
        int b = idx >> 16, s = (idx >> 5) & 2047, i = idx & 31;
        float p = (float)tp[(b << 11) + s];
        float freq = exp2f(-(float)i * FREQ_L);
        float sn, cs;
        sincosf(p * freq, &sn, &cs);
        tab[idx] = make_float2(cs, sn);
    }
}

// ---------------------------------------------------------------- fused QKV GEMM + RoPE
// Round-6 version KEPT (below 69.5 us; was 75.2 at round-5).  Phase-interleaved
// counted-vmcnt schedule, BK=64/phase, 16 phases, 3 slots x 48 KB = 144 KB LDS.
// Proven conflict-free BK=64 addressing (stage (Lc&7)^(row&7), read
// ((kc*4+quad)^l7)*8).  Per phase: vmcnt(6) -> raw s_barrier -> sched_barrier
// -> stage(h+2) -> {2 kc: 8 ds_read_b128 + setprio(1) 16 MFMA setprio(0)}.
// BM=256, BN=128; 512 threads = 8 waves (4Mx2N); grid 768 = 3 CU-rounds.
__global__ __launch_bounds__(512) void gemm_qkv(const short* __restrict__ A,
                                                const short* __restrict__ Bq,
                                                const short* __restrict__ Bk,
                                                const short* __restrict__ Bv,
                                                const float2* __restrict__ tab,
                                                short* __restrict__ Qo,
                                                short* __restrict__ Ko,
                                                short* __restrict__ Vo) {
    constexpr int K = 1024;
    // 3 slots x 24576 shorts (A tile 256x64 = 16384 + B tile 128x64 = 8192)
    __shared__ __align__(16) short smem[3 * 24576];

    const int sel = blockIdx.x >> 3;
    const int bn = blockIdx.x & 7;
    const int bm = blockIdx.y;
    const short* Bm = sel == 0 ? Bq : sel == 1 ? Bk : Bv;
    short* Cb = sel == 0 ? Qo : sel == 1 ? Ko : Vo;

    const int tid = threadIdx.x;
    const int lane = tid & 63;
    const int w = tid >> 6;          // 0..7
    const int wm = w >> 1;           // 0..3  (M-waves)
    const int wn = w & 1;            // 0..1  (N-waves)
    const int quad = lane >> 4, l16 = lane & 15;
    const int l7 = l16 & 7;

    int aoff[4], boff[2];
#pragma unroll
    for (int i = 0; i < 4; i++) {
        int Lc = i * 512 + tid;
        int row = Lc >> 3;
        int cc = (Lc & 7) ^ (row & 7);
        aoff[i] = (bm * 256 + row) * K + cc * 8;
    }
#pragma unroll
    for (int i = 0; i < 2; i++) {
        int Lc = i * 512 + tid;
        int row = Lc >> 3;
        int cc = (Lc & 7) ^ (row & 7);
        boff[i] = (bn * 128 + row) * K + cc * 8;
    }

    auto stage = [&](int h, int slot) {
        char* sbase = (char*)smem + slot * 49152;
        const int kh = h * 64;
#pragma unroll
        for (int i = 0; i < 4; i++)
            GLDS(A + aoff[i] + kh, sbase + i * 8192 + w * 1024);
#pragma unroll
        for (int i = 0; i < 2; i++)
            GLDS(Bm + boff[i] + kh, sbase + 32768 + i * 8192 + w * 1024);
    };

    f32x4 acc[4][4] = {};

    auto compute = [&](int slot) {
        const short* sA = smem + slot * 24576;
        const short* sB = sA + 16384;
#pragma unroll
        for (int kc = 0; kc < 2; kc++) {
            const int c = ((kc * 4 + quad) ^ l7) * 8;
            bf16x8 af[4], bfm[4];
#pragma unroll
            for (int mi = 0; mi < 4; mi++)
                af[mi] = *(const bf16x8*)&sA[(wm * 64 + mi * 16 + l16) * 64 + c];
#pragma unroll
            for (int ni = 0; ni < 4; ni++)
                bfm[ni] = *(const bf16x8*)&sB[(wn * 64 + ni * 16 + l16) * 64 + c];
            __builtin_amdgcn_s_setprio(1);
#pragma unroll
            for (int mi = 0; mi < 4; mi++)
#pragma unroll
                for (int ni = 0; ni < 4; ni++)
                    acc[mi][ni] = __builtin_amdgcn_mfma_f32_16x16x32_bf16(af[mi], bfm[ni],
                                                                          acc[mi][ni], 0, 0, 0);
            __builtin_amdgcn_s_setprio(0);
        }
    };

    // prologue: 2 tiles in flight (12 loads)
    stage(0, 0); stage(1, 1);

    auto step = [&](int h, int sc, int ss) {
        asm volatile("s_waitcnt vmcnt(6)" ::: "memory");   // tile h complete
        __builtin_amdgcn_s_barrier();
        __builtin_amdgcn_sched_barrier(0);
        stage(h + 2, ss);
        compute(sc);
    };

    for (int h = 0; h < 12; h += 3) {
        step(h + 0, 0, 2);
        step(h + 1, 1, 0);
        step(h + 2, 2, 1);
    }
    step(12, 0, 2);
    step(13, 1, 0);
    // h = 14: tile 15's 6 loads still in flight
    asm volatile("s_waitcnt vmcnt(6)" ::: "memory");
    __builtin_amdgcn_s_barrier();
    __builtin_amdgcn_sched_barrier(0);
    compute(2);
    // h = 15: final drain
    asm volatile("s_waitcnt vmcnt(0)" ::: "memory");
    __builtin_amdgcn_s_barrier();
    __builtin_amdgcn_sched_barrier(0);
    compute(0);

    const int gm0 = bm * 256 + wm * 64;
    const int gn0 = bn * 128 + wn * 64;

    if (sel == 2) {
        // ---- V^T -> [B][H][64][S] via LDS transpose (re-use staging LDS).
        short* T = smem;
        __syncthreads();   // all phases' LDS reads done before overwrite
#pragma unroll
        for (int mi = 0; mi < 4; mi++) {
            int lmb = wm * 64 + mi * 16 + quad * 4;        // s-local base (mult of 4)
#pragma unroll
            for (int ni = 0; ni < 4; ni++) {
                int ln = wn * 64 + ni * 16 + l16;          // hd-local row 0..127
                short4 pk;
                pk.x = f2bf(acc[mi][ni][0]);
                pk.y = f2bf(acc[mi][ni][1]);
                pk.z = f2bf(acc[mi][ni][2]);
                pk.w = f2bf(acc[mi][ni][3]);
                *(short4*)&T[ln * 256 + (lmb ^ ((ln & 31) << 3))] = pk;
            }
        }
        __syncthreads();
        const int row = tid >> 2, qt = tid & 3;
        const int grow = bn * 128 + row;                   // global hd-row
        const int gb = bm >> 3;                            // batch
        const int gs0 = (bm & 7) * 256;
        short* dst = Cb + (((size_t)(gb * NH + (grow >> 6)) * HDIM + (grow & 63)) * S_LEN
                           + gs0 + qt * 64);
#pragma unroll
        for (int j = 0; j < 8; j++) {
            bf16x8 v = *(const bf16x8*)&T[row * 256 +
                        ((qt * 64 + j * 8) ^ ((row & 31) << 3))];
            *(bf16x8*)(dst + j * 8) = v;
        }
    } else {
        // Q/K with fused RoPE (table lookup); pair (hd, hd^1) in adjacent lanes
        const float qs = (sel == 0) ? QSCALE : 1.0f;
#pragma unroll
        for (int mi = 0; mi < 4; mi++)
#pragma unroll
            for (int r = 0; r < 4; r++) {
                int gm = gm0 + mi * 16 + quad * 4 + r;        // b*2048 + s
                const float2* trow = tab + (gm << 5);
                int b = gm >> 11, s = gm & 2047;
#pragma unroll
                for (int ni = 0; ni < 4; ni++) {
                    float2 cs = trow[ni * 8 + (l16 >> 1)];
                    float v = acc[mi][ni][r];
                    float prt = __shfl_xor(v, 1, 64);
                    float val = (l16 & 1) ? (prt * cs.y + v * cs.x)
                                          : (v * cs.x - prt * cs.y);
                    int gn = gn0 + ni * 16 + l16;
                    int h = gn >> 6, hd = gn & 63;
                    Cb[((b * NH + h) * S_LEN + s) * HDIM + hd] = f2bf(val * qs);
                }
            }
    }
}

// ---------------------------------------------------------------- O-projection GEMM
// Round-1 version KEPT.  128x64 tiles, BK=32, 3-buffer counted-vmcnt pipeline
// (3 loads/tile -> vmcnt(3)), raw s_barrier.  LDS 36 KB.  grid (16, 64).
__global__ __launch_bounds__(256) void gemm_o(const short* __restrict__ A,
                                              const short* __restrict__ Bw,
                                              float* __restrict__ Cf) {
    constexpr int N = 1024, K = 1024, BK = 32;
    __shared__ __align__(16) short sa[3][128 * BK];  // 3 x 8 KB
    __shared__ __align__(16) short sb[3][64 * BK];   // 3 x 4 KB

    const int tid = threadIdx.x;
    const int lane = tid & 63;
    const int w = tid >> 6;
    const int quad = lane >> 4, l16 = lane & 15;
    const int bn = blockIdx.x, bm = blockIdx.y;
    const int arow0 = bm * 128, brow0 = bn * 64;

    int aoff[2], boff;
#pragma unroll
    for (int i = 0; i < 2; i++) {
        int cs = i * 256 + tid;
        int row = cs >> 2;
        int gc = (cs & 3) ^ ((row >> 1) & 3);
        aoff[i] = (arow0 + row) * K + gc * 8;
    }
    {
        int row = tid >> 2;
        int gc = (tid & 3) ^ ((row >> 1) & 3);
        boff = (brow0 + row) * K + gc * 8;
    }

    auto stage = [&](int kt, int b) {
        const int k0 = kt * BK;
#pragma unroll
        for (int i = 0; i < 2; i++)
            GLDS(A + aoff[i] + k0, (char*)&sa[b][0] + i * 4096 + w * 1024);
        GLDS(Bw + boff + k0, (char*)&sb[b][0] + w * 1024);
    };

    f32x4 acc[2][4] = {};
    const int rsw = (quad ^ ((l16 >> 1) & 3)) * 8;

    auto compute = [&](int b) {
        bf16x8 af[2];
#pragma unroll
        for (int mi = 0; mi < 2; mi++)
            af[mi] = *(const bf16x8*)&sa[b][(w * 32 + mi * 16 + l16) * BK + rsw];
#pragma unroll
        for (int ni = 0; ni < 4; ni++) {
            bf16x8 bfr = *(const bf16x8*)&sb[b][(ni * 16 + l16) * BK + rsw];
#pragma unroll
            for (int mi = 0; mi < 2; mi++)
                acc[mi][ni] = __builtin_amdgcn_mfma_f32_16x16x32_bf16(af[mi], bfr,
                                                                     acc[mi][ni], 0, 0, 0);
        }
    };

    stage(0, 0);
    stage(1, 1);

    auto step = [&](int kt, int b, int bs) {
        asm volatile("s_waitcnt vmcnt(3)" ::: "memory");
        __builtin_amdgcn_s_barrier();
        __builtin_amdgcn_sched_barrier(0);
        stage(kt + 2, bs);
        compute(b);
    };

    for (int kt = 0; kt < 30; kt += 3) {
        step(kt + 0, 0, 2);
        step(kt + 1, 1, 0);
        step(kt + 2, 2, 1);
    }
    // kt = 30
    asm volatile("s_waitcnt vmcnt(3)" ::: "memory");
    __builtin_amdgcn_s_barrier();
    __builtin_amdgcn_sched_barrier(0);
    compute(0);
    // kt = 31
    asm volatile("s_waitcnt vmcnt(0)" ::: "memory");
    __builtin_amdgcn_s_barrier();
    __builtin_amdgcn_sched_barrier(0);
    compute(1);

    const int gm0 = arow0 + w * 32;
#pragma unroll
    for (int mi = 0; mi < 2; mi++)
#pragma unroll
        for (int ni = 0; ni < 4; ni++)
#pragma unroll
            for (int r = 0; r < 4; r++) {
                int gm = gm0 + mi * 16 + quad * 4 + r;
                int gn = brow0 + ni * 16 + l16;
                Cf[gm * N + gn] = acc[mi][ni][r];
            }
}

// ---------------------------------------------------------------- flash attention (causal)
// Q,K: [BH][S][64] bf16 (Q pre-scaled by 0.125*log2e), Vt: [BH][64][S] bf16,
// O: [B][S][D] bf16.  Fixed-max softmax (scores O(0.2); masked -> exp2(-inf)=0).
// Round-7: OCCUPANCY 2 -> 3 blocks/CU.  Round-6 counters: MfmaUtil 23%,
// VALUBusy 25%, Occ 18.8%, conflicts 0, HBM 30% -> latency/dependency-bound
// at 2 waves/SIMD.  LDS 48 KB/block fits 3/CU (144<=160 KB) but the paired
// grid (8,64)=512 pinned 2/CU.  Un-pair: grid (16,64)=1024 single-Qt blocks,
// Qt = 15 - blockIdx.x (longest blocks dispatch FIRST per bh row -> tail
// containment).  Inner loop byte-identical; one phase instead of two.
__global__ __launch_bounds__(256, 3) void attn(const short* __restrict__ Q,
                                               const short* __restrict__ Km,
                                               const short* __restrict__ Vt,
                                               short* __restrict__ O) {
    __shared__ __align__(16) short kbuf[2][64 * 64];   // 16 KB
    __shared__ __align__(16) short vbuf[2][64 * 64];   // 16 KB
    __shared__ __align__(16) short pbuf[4][32 * 64];   // 16 KB (per-wave private)

    const int lane = threadIdx.x & 63;
    const int w = threadIdx.x >> 6;
    const int quad = lane >> 4, l16 = lane & 15;
    const int l7 = l16 & 7;
    const int bh = blockIdx.y;

    const short* Qg = Q  + bh * S_LEN * 64;
    const short* Kg = Km + bh * S_LEN * 64;
    const short* Vg = Vt + bh * 64 * S_LEN;
    short* myp = &pbuf[w][0];

    const int b = bh >> 4, h = bh & 15;

    bf16x8 ones;
#pragma unroll
    for (int j = 0; j < 8; j++) ones[j] = (short)0x3f80;   // bf16 1.0

    auto stage = [&](int kt, int par) {
        const short* kt_base = Kg + kt * 64 * 64;
        const short* vt_base = Vg + kt * 64;
#pragma unroll
        for (int i = 0; i < 2; ++i) {
            int ch = w * 128 + i * 64 + lane;
            int row = ch >> 3;
            int c = (ch & 7) ^ (row & 7);
            GLDS(kt_base + row * 64 + c * 8, (char*)&kbuf[par][(w * 128 + i * 64) * 8]);
        }
#pragma unroll
        for (int i = 0; i < 2; ++i) {
            int ch = w * 128 + i * 64 + lane;
            int row = ch >> 3;
            int c = (ch & 7) ^ (row & 7);
            GLDS(vt_base + row * S_LEN + c * 8, (char*)&vbuf[par][(w * 128 + i * 64) * 8]);
        }
    };

    const int Qt = 15 - blockIdx.x;    // longest-first dispatch
    const int nkt = 2 * Qt + 2;

    stage(0, 0);

    bf16x8 aq[2][2];
#pragma unroll
    for (int mi = 0; mi < 2; mi++) {
        int qrow = Qt * 128 + w * 32 + mi * 16 + l16;
#pragma unroll
        for (int kc = 0; kc < 2; kc++)
            aq[mi][kc] = *(const bf16x8*)&Qg[qrow * 64 + kc * 32 + quad * 8];
    }

    f32x4 oacc[2][4] = {};
    f32x4 lacc[2] = {};

    for (int kt = 0; kt < nkt; ++kt) {
        __syncthreads();   // tile (kt&1) ready; prior reads of other buffer drained
        if (kt + 1 < nkt) stage(kt + 1, (kt + 1) & 1);
        const short* kb_cur = &kbuf[kt & 1][0];
        const short* vb_cur = &vbuf[kt & 1][0];

        // ---- S = Q K^T  (independent chains: 2 mi x 4 nt)
        f32x4 sc[2][4] = {};
#pragma unroll
        for (int nt = 0; nt < 4; nt++) {
            int raddr = (nt * 16 + l16) * 64;
#pragma unroll
            for (int kc = 0; kc < 2; kc++) {
                bf16x8 kf = *(const bf16x8*)&kb_cur[raddr + (((quad + kc * 4) ^ l7) * 8)];
                sc[0][nt] = __builtin_amdgcn_mfma_f32_16x16x32_bf16(aq[0][kc], kf, sc[0][nt], 0, 0, 0);
                sc[1][nt] = __builtin_amdgcn_mfma_f32_16x16x32_bf16(aq[1][kc], kf, sc[1][nt], 0, 0, 0);
            }
        }
        // ---- causal mask (only last two tiles hit the diagonal)
        if (kt >= nkt - 2) {
#pragma unroll
            for (int mi = 0; mi < 2; mi++)
#pragma unroll
                for (int nt = 0; nt < 4; nt++)
#pragma unroll
                    for (int r = 0; r < 4; r++) {
                        int col = kt * 64 + nt * 16 + l16;
                        int row = Qt * 128 + w * 32 + mi * 16 + quad * 4 + r;
                        if (col > row) sc[mi][nt][r] = -__builtin_inff();
                    }
        }
        // ---- p = exp2(s); truncated bf16 store (d16_hi, zero VALU convert)
#pragma unroll
        for (int mi = 0; mi < 2; mi++)
#pragma unroll
            for (int nt = 0; nt < 4; nt++)
#pragma unroll
                for (int r = 0; r < 4; r++) {
                    float pv = __builtin_amdgcn_exp2f(sc[mi][nt][r]);
                    int q = mi * 16 + quad * 4 + r;
                    union { float f; unsigned short us[2]; } uu;
                    uu.f = pv;
                    myp[q * 64 + (((nt * 2 + (l16 >> 3)) ^ (q & 7)) * 8) + l7] =
                        (short)uu.us[1];
                }
        // ---- P: LDS -> A-frags (in-wave DS ordering; no barrier needed)
        bf16x8 ap[2][2];
#pragma unroll
        for (int mi = 0; mi < 2; mi++)
#pragma unroll
            for (int kc = 0; kc < 2; kc++)
                ap[mi][kc] = *(const bf16x8*)&myp[(mi * 16 + l16) * 64 +
                                                  (((quad + kc * 4) ^ l7) * 8)];
        // ---- O += P V ; denominator += P * ones (MFMA pipe)
#pragma unroll
        for (int nt = 0; nt < 4; nt++) {
            int raddr = (nt * 16 + l16) * 64;
#pragma unroll
            for (int kc = 0; kc < 2; kc++) {
                bf16x8 vf = *(const bf16x8*)&vb_cur[raddr + (((quad + kc * 4) ^ l7) * 8)];
                oacc[0][nt] = __builtin_amdgcn_mfma_f32_16x16x32_bf16(ap[0][kc], vf, oacc[0][nt], 0, 0, 0);
                oacc[1][nt] = __builtin_amdgcn_mfma_f32_16x16x32_bf16(ap[1][kc], vf, oacc[1][nt], 0, 0, 0);
            }
        }
#pragma unroll
        for (int mi = 0; mi < 2; mi++) {
            lacc[mi] = __builtin_amdgcn_mfma_f32_16x16x32_bf16(ap[mi][0], ones, lacc[mi], 0, 0, 0);
            lacc[mi] = __builtin_amdgcn_mfma_f32_16x16x32_bf16(ap[mi][1], ones, lacc[mi], 0, 0, 0);
        }
    }
    // ---- epilogue: lacc holds per-row denominators (all cols equal)
#pragma unroll
    for (int mi = 0; mi < 2; mi++)
#pragma unroll
        for (int r = 0; r < 4; r++) {
            float inv = 1.0f / lacc[mi][r];
            int srow = Qt * 128 + w * 32 + mi * 16 + quad * 4 + r;
#pragma unroll
            for (int nt = 0; nt < 4; nt++) {
                int hd = nt * 16 + l16;
                O[(b * S_LEN + srow) * DMODEL + h * HDIM + hd] = f2bf(oacc[mi][nt][r] * inv);
            }
        }
}

// ---------------------------------------------------------------- launch
extern "C" void kernel_launch(void* const* d_in, const int* in_sizes, int n_in,
                              void* d_out, int out_size, void* d_ws, size_t ws_size,
                              hipStream_t stream) {
    const float* x  = (const float*)d_in[0];
    const int*   tp = (const int*)d_in[1];
    const float* Wq = (const float*)d_in[2];
    const float* Wk = (const float*)d_in[3];
    const float* Wv = (const float*)d_in[4];
    const float* Wo = (const float*)d_in[5];
    float* out = (float*)d_out;

    char* ws = (char*)d_ws;
    const size_t MB = 1024 * 1024;
    short* xb  = (short*)(ws);             // 16 MB: x bf16 [8192][1024]; reused as o_buf
    short* wqb = (short*)(ws + 16 * MB);
    short* wkb = (short*)(ws + 18 * MB);
    short* wvb = (short*)(ws + 20 * MB);
    short* wob = (short*)(ws + 22 * MB);
    short* Qb  = (short*)(ws + 24 * MB);   // 16 MB [BH][S][64]
    short* Kb  = (short*)(ws + 40 * MB);   // 16 MB [BH][S][64]
    short* Vtb = (short*)(ws + 56 * MB);   // 16 MB [BH][64][S]
    // RoPE table (2 MB) lives in d_out: scratch until gemm_o overwrites it.
    float2* tab = (float2*)d_out;

    prep<<<13312, 256, 0, stream>>>(x, Wq, Wk, Wv, Wo, tp,
                                    xb, wqb, wkb, wvb, wob, tab);

    gemm_qkv<<<dim3(24, 32), 512, 0, stream>>>(xb, wqb, wkb, wvb, tab, Qb, Kb, Vtb);

    attn<<<dim3(16, 64), 256, 0, stream>>>(Qb, Kb, Vtb, xb);

    gemm_o<<<dim3(16, 64), 256, 0, stream>>>(xb, wob, out);
}

// Round 8
// 247.954 us; speedup vs baseline: 1.2055x; 1.2055x over previous
//
#include <hip/hip_runtime.h>

// Problem constants: B=4, S=2048, D=1024, H=16, HD=64
#define S_LEN 2048
#define NH 16
#define HDIM 64
#define DMODEL 1024

typedef __attribute__((ext_vector_type(8))) short bf16x8;
typedef __attribute__((ext_vector_type(4))) float f32x4;

__device__ __forceinline__ short f2bf(float f) {
    union { float f; unsigned u; } x; x.f = f;
    unsigned r = x.u + 0x7fffu + ((x.u >> 16) & 1u);  // round-to-nearest-even
    return (short)(r >> 16);
}

#define GLDS(g, l) __builtin_amdgcn_global_load_lds( \
    (__attribute__((address_space(1))) void*)(g),    \
    (__attribute__((address_space(3))) void*)(l), 16, 0, 0)

#define QSCALE 0.18033688011112042f   // 0.125 * log2(e)
#define FREQ_L 0.41524101186109327f   // log2(10000)/32

// ---------------------------------------------------------------- prep (one launch)
// blocks [0,8192):      cast x (f32 -> bf16)
// blocks [8192,12288):  cast Wq/Wk/Wv/Wo
// blocks [12288,13312): RoPE cos/sin table [B][S][32] float2
__global__ __launch_bounds__(256) void prep(const float* __restrict__ x,
                                            const float* __restrict__ wq,
                                            const float* __restrict__ wk,
                                            const float* __restrict__ wv,
                                            const float* __restrict__ wo,
                                            const int* __restrict__ tp,
                                            short* __restrict__ xb,
                                            short* __restrict__ wqb,
                                            short* __restrict__ wkb,
                                            short* __restrict__ wvb,
                                            short* __restrict__ wob,
                                            float2* __restrict__ tab) {
    int bid = blockIdx.x;
    if (bid < 8192) {
        int i = bid * 256 + threadIdx.x;
        float4 v = ((const float4*)x)[i];
        short4 o;
        o.x = f2bf(v.x); o.y = f2bf(v.y); o.z = f2bf(v.z); o.w = f2bf(v.w);
        ((short4*)xb)[i] = o;
    } else if (bid < 12288) {
        int sel = (bid - 8192) >> 10;
        const float* in = sel == 0 ? wq : sel == 1 ? wk : sel == 2 ? wv : wo;
        short* out = sel == 0 ? wqb : sel == 1 ? wkb : sel == 2 ? wvb : wob;
        int i = ((bid - 8192) & 1023) * 256 + threadIdx.x;
        float4 v = ((const float4*)in)[i];
        short4 o;
        o.x = f2bf(v.x); o.y = f2bf(v.y); o.z = f2bf(v.z); o.w = f2bf(v.w);
        ((short4*)out)[i] = o;
    } else {
        int idx = (bid - 12288) * 256 + threadIdx.x;   // < 262144
        int b = idx >> 16, s = (idx >> 5) & 2047, i = idx & 31;
        float p = (float)tp[(b << 11) + s];
        float freq = exp2f(-(float)i * FREQ_L);
        float sn, cs;
        sincosf(p * freq, &sn, &cs);
        tab[idx] = make_float2(cs, sn);
    }
}

// ---------------------------------------------------------------- fused QKV GEMM + RoPE
// Round-6 version KEPT.  Phase-interleaved counted-vmcnt schedule, BK=64/phase,
// 16 phases, 3 slots x 48 KB = 144 KB LDS.  Proven conflict-free BK=64
// addressing (stage (Lc&7)^(row&7), read ((kc*4+quad)^l7)*8).  Per phase:
// vmcnt(6) -> raw s_barrier -> sched_barrier -> stage(h+2) -> {2 kc: 8
// ds_read_b128 + setprio(1) 16 MFMA setprio(0)}.  BM=256, BN=128; 512 threads
// = 8 waves (4Mx2N); grid 768 = 3 CU-rounds.
__global__ __launch_bounds__(512) void gemm_qkv(const short* __restrict__ A,
                                                const short* __restrict__ Bq,
                                                const short* __restrict__ Bk,
                                                const short* __restrict__ Bv,
                                                const float2* __restrict__ tab,
                                                short* __restrict__ Qo,
                                                short* __restrict__ Ko,
                                                short* __restrict__ Vo) {
    constexpr int K = 1024;
    __shared__ __align__(16) short smem[3 * 24576];

    const int sel = blockIdx.x >> 3;
    const int bn = blockIdx.x & 7;
    const int bm = blockIdx.y;
    const short* Bm = sel == 0 ? Bq : sel == 1 ? Bk : Bv;
    short* Cb = sel == 0 ? Qo : sel == 1 ? Ko : Vo;

    const int tid = threadIdx.x;
    const int lane = tid & 63;
    const int w = tid >> 6;          // 0..7
    const int wm = w >> 1;           // 0..3  (M-waves)
    const int wn = w & 1;            // 0..1  (N-waves)
    const int quad = lane >> 4, l16 = lane & 15;
    const int l7 = l16 & 7;

    int aoff[4], boff[2];
#pragma unroll
    for (int i = 0; i < 4; i++) {
        int Lc = i * 512 + tid;
        int row = Lc >> 3;
        int cc = (Lc & 7) ^ (row & 7);
        aoff[i] = (bm * 256 + row) * K + cc * 8;
    }
#pragma unroll
    for (int i = 0; i < 2; i++) {
        int Lc = i * 512 + tid;
        int row = Lc >> 3;
        int cc = (Lc & 7) ^ (row & 7);
        boff[i] = (bn * 128 + row) * K + cc * 8;
    }

    auto stage = [&](int h, int slot) {
        char* sbase = (char*)smem + slot * 49152;
        const int kh = h * 64;
#pragma unroll
        for (int i = 0; i < 4; i++)
            GLDS(A + aoff[i] + kh, sbase + i * 8192 + w * 1024);
#pragma unroll
        for (int i = 0; i < 2; i++)
            GLDS(Bm + boff[i] + kh, sbase + 32768 + i * 8192 + w * 1024);
    };

    f32x4 acc[4][4] = {};

    auto compute = [&](int slot) {
        const short* sA = smem + slot * 24576;
        const short* sB = sA + 16384;
#pragma unroll
        for (int kc = 0; kc < 2; kc++) {
            const int c = ((kc * 4 + quad) ^ l7) * 8;
            bf16x8 af[4], bfm[4];
#pragma unroll
            for (int mi = 0; mi < 4; mi++)
                af[mi] = *(const bf16x8*)&sA[(wm * 64 + mi * 16 + l16) * 64 + c];
#pragma unroll
            for (int ni = 0; ni < 4; ni++)
                bfm[ni] = *(const bf16x8*)&sB[(wn * 64 + ni * 16 + l16) * 64 + c];
            __builtin_amdgcn_s_setprio(1);
#pragma unroll
            for (int mi = 0; mi < 4; mi++)
#pragma unroll
                for (int ni = 0; ni < 4; ni++)
                    acc[mi][ni] = __builtin_amdgcn_mfma_f32_16x16x32_bf16(af[mi], bfm[ni],
                                                                          acc[mi][ni], 0, 0, 0);
            __builtin_amdgcn_s_setprio(0);
        }
    };

    stage(0, 0); stage(1, 1);

    auto step = [&](int h, int sc, int ss) {
        asm volatile("s_waitcnt vmcnt(6)" ::: "memory");   // tile h complete
        __builtin_amdgcn_s_barrier();
        __builtin_amdgcn_sched_barrier(0);
        stage(h + 2, ss);
        compute(sc);
    };

    for (int h = 0; h < 12; h += 3) {
        step(h + 0, 0, 2);
        step(h + 1, 1, 0);
        step(h + 2, 2, 1);
    }
    step(12, 0, 2);
    step(13, 1, 0);
    asm volatile("s_waitcnt vmcnt(6)" ::: "memory");
    __builtin_amdgcn_s_barrier();
    __builtin_amdgcn_sched_barrier(0);
    compute(2);
    asm volatile("s_waitcnt vmcnt(0)" ::: "memory");
    __builtin_amdgcn_s_barrier();
    __builtin_amdgcn_sched_barrier(0);
    compute(0);

    const int gm0 = bm * 256 + wm * 64;
    const int gn0 = bn * 128 + wn * 64;

    if (sel == 2) {
        // ---- V^T -> [B][H][64][S] via LDS transpose (re-use staging LDS).
        short* T = smem;
        __syncthreads();
#pragma unroll
        for (int mi = 0; mi < 4; mi++) {
            int lmb = wm * 64 + mi * 16 + quad * 4;
#pragma unroll
            for (int ni = 0; ni < 4; ni++) {
                int ln = wn * 64 + ni * 16 + l16;
                short4 pk;
                pk.x = f2bf(acc[mi][ni][0]);
                pk.y = f2bf(acc[mi][ni][1]);
                pk.z = f2bf(acc[mi][ni][2]);
                pk.w = f2bf(acc[mi][ni][3]);
                *(short4*)&T[ln * 256 + (lmb ^ ((ln & 31) << 3))] = pk;
            }
        }
        __syncthreads();
        const int row = tid >> 2, qt = tid & 3;
        const int grow = bn * 128 + row;
        const int gb = bm >> 3;
        const int gs0 = (bm & 7) * 256;
        short* dst = Cb + (((size_t)(gb * NH + (grow >> 6)) * HDIM + (grow & 63)) * S_LEN
                           + gs0 + qt * 64);
#pragma unroll
        for (int j = 0; j < 8; j++) {
            bf16x8 v = *(const bf16x8*)&T[row * 256 +
                        ((qt * 64 + j * 8) ^ ((row & 31) << 3))];
            *(bf16x8*)(dst + j * 8) = v;
        }
    } else {
        const float qs = (sel == 0) ? QSCALE : 1.0f;
#pragma unroll
        for (int mi = 0; mi < 4; mi++)
#pragma unroll
            for (int r = 0; r < 4; r++) {
                int gm = gm0 + mi * 16 + quad * 4 + r;        // b*2048 + s
                const float2* trow = tab + (gm << 5);
                int b = gm >> 11, s = gm & 2047;
#pragma unroll
                for (int ni = 0; ni < 4; ni++) {
                    float2 cs = trow[ni * 8 + (l16 >> 1)];
                    float v = acc[mi][ni][r];
                    float prt = __shfl_xor(v, 1, 64);
                    float val = (l16 & 1) ? (prt * cs.y + v * cs.x)
                                          : (v * cs.x - prt * cs.y);
                    int gn = gn0 + ni * 16 + l16;
                    int h = gn >> 6, hd = gn & 63;
                    Cb[((b * NH + h) * S_LEN + s) * HDIM + hd] = f2bf(val * qs);
                }
            }
    }
}

// ---------------------------------------------------------------- O-projection GEMM
// Round-1 version KEPT.  128x64 tiles, BK=32, 3-buffer counted-vmcnt pipeline
// (3 loads/tile -> vmcnt(3)), raw s_barrier.  LDS 36 KB.  grid (16, 64).
__global__ __launch_bounds__(256) void gemm_o(const short* __restrict__ A,
                                              const short* __restrict__ Bw,
                                              float* __restrict__ Cf) {
    constexpr int N = 1024, K = 1024, BK = 32;
    __shared__ __align__(16) short sa[3][128 * BK];  // 3 x 8 KB
    __shared__ __align__(16) short sb[3][64 * BK];   // 3 x 4 KB

    const int tid = threadIdx.x;
    const int lane = tid & 63;
    const int w = tid >> 6;
    const int quad = lane >> 4, l16 = lane & 15;
    const int bn = blockIdx.x, bm = blockIdx.y;
    const int arow0 = bm * 128, brow0 = bn * 64;

    int aoff[2], boff;
#pragma unroll
    for (int i = 0; i < 2; i++) {
        int cs = i * 256 + tid;
        int row = cs >> 2;
        int gc = (cs & 3) ^ ((row >> 1) & 3);
        aoff[i] = (arow0 + row) * K + gc * 8;
    }
    {
        int row = tid >> 2;
        int gc = (tid & 3) ^ ((row >> 1) & 3);
        boff = (brow0 + row) * K + gc * 8;
    }

    auto stage = [&](int kt, int b) {
        const int k0 = kt * BK;
#pragma unroll
        for (int i = 0; i < 2; i++)
            GLDS(A + aoff[i] + k0, (char*)&sa[b][0] + i * 4096 + w * 1024);
        GLDS(Bw + boff + k0, (char*)&sb[b][0] + w * 1024);
    };

    f32x4 acc[2][4] = {};
    const int rsw = (quad ^ ((l16 >> 1) & 3)) * 8;

    auto compute = [&](int b) {
        bf16x8 af[2];
#pragma unroll
        for (int mi = 0; mi < 2; mi++)
            af[mi] = *(const bf16x8*)&sa[b][(w * 32 + mi * 16 + l16) * BK + rsw];
#pragma unroll
        for (int ni = 0; ni < 4; ni++) {
            bf16x8 bfr = *(const bf16x8*)&sb[b][(ni * 16 + l16) * BK + rsw];
#pragma unroll
            for (int mi = 0; mi < 2; mi++)
                acc[mi][ni] = __builtin_amdgcn_mfma_f32_16x16x32_bf16(af[mi], bfr,
                                                                     acc[mi][ni], 0, 0, 0);
        }
    };

    stage(0, 0);
    stage(1, 1);

    auto step = [&](int kt, int b, int bs) {
        asm volatile("s_waitcnt vmcnt(3)" ::: "memory");
        __builtin_amdgcn_s_barrier();
        __builtin_amdgcn_sched_barrier(0);
        stage(kt + 2, bs);
        compute(b);
    };

    for (int kt = 0; kt < 30; kt += 3) {
        step(kt + 0, 0, 2);
        step(kt + 1, 1, 0);
        step(kt + 2, 2, 1);
    }
    asm volatile("s_waitcnt vmcnt(3)" ::: "memory");
    __builtin_amdgcn_s_barrier();
    __builtin_amdgcn_sched_barrier(0);
    compute(0);
    asm volatile("s_waitcnt vmcnt(0)" ::: "memory");
    __builtin_amdgcn_s_barrier();
    __builtin_amdgcn_sched_barrier(0);
    compute(1);

    const int gm0 = arow0 + w * 32;
#pragma unroll
    for (int mi = 0; mi < 2; mi++)
#pragma unroll
        for (int ni = 0; ni < 4; ni++)
#pragma unroll
            for (int r = 0; r < 4; r++) {
                int gm = gm0 + mi * 16 + quad * 4 + r;
                int gn = brow0 + ni * 16 + l16;
                Cf[gm * N + gn] = acc[mi][ni][r];
            }
}

// ---------------------------------------------------------------- flash attention (causal)
// Q,K: [BH][S][64] bf16 (Q pre-scaled by 0.125*log2e), Vt: [BH][64][S] bf16,
// O: [B][S][D] bf16.  Fixed-max softmax (scores O(0.2); masked -> exp2(-inf)=0).
// Round-8: REVERT to the paired round-6 structure (69.5 us proven).  Round-7's
// un-paired grid regressed to 103.7 us: block lengths 2..32 iters -> load
// imbalance, occupancy fell 18.8->13.7%.  The pairing (Qt, 15-Qt) gives
// UNIFORM 34 iters/block — that uniformity is load-balance-critical.
// NEW vs round-6: T5 s_setprio(1) around the QK^T and PV MFMA clusters
// (guide m191: +4-7% attn; 8 waves/CU drift between barriers, so MFMA-
// entering waves win pipe arbitration over exp2/LDS-issuing waves).
// grid (8,64)=512 = 2 blocks/CU.
__global__ __launch_bounds__(256, 3) void attn(const short* __restrict__ Q,
                                               const short* __restrict__ Km,
                                               const short* __restrict__ Vt,
                                               short* __restrict__ O) {
    __shared__ __align__(16) short kbuf[2][64 * 64];   // 16 KB
    __shared__ __align__(16) short vbuf[2][64 * 64];   // 16 KB
    __shared__ __align__(16) short pbuf[4][32 * 64];   // 16 KB (per-wave private)

    const int lane = threadIdx.x & 63;
    const int w = threadIdx.x >> 6;
    const int quad = lane >> 4, l16 = lane & 15;
    const int l7 = l16 & 7;
    const int bh = blockIdx.y;

    const short* Qg = Q  + bh * S_LEN * 64;
    const short* Kg = Km + bh * S_LEN * 64;
    const short* Vg = Vt + bh * 64 * S_LEN;
    short* myp = &pbuf[w][0];

    const int b = bh >> 4, h = bh & 15;

    bf16x8 ones;
#pragma unroll
    for (int j = 0; j < 8; j++) ones[j] = (short)0x3f80;   // bf16 1.0

    auto stage = [&](int kt, int par) {
        const short* kt_base = Kg + kt * 64 * 64;
        const short* vt_base = Vg + kt * 64;
#pragma unroll
        for (int i = 0; i < 2; ++i) {
            int ch = w * 128 + i * 64 + lane;
            int row = ch >> 3;
            int c = (ch & 7) ^ (row & 7);
            GLDS(kt_base + row * 64 + c * 8, (char*)&kbuf[par][(w * 128 + i * 64) * 8]);
        }
#pragma unroll
        for (int i = 0; i < 2; ++i) {
            int ch = w * 128 + i * 64 + lane;
            int row = ch >> 3;
            int c = (ch & 7) ^ (row & 7);
            GLDS(vt_base + row * S_LEN + c * 8, (char*)&vbuf[par][(w * 128 + i * 64) * 8]);
        }
    };

    const int QtA = blockIdx.x;        // 0..7
    const int QtB = 15 - blockIdx.x;   // 15..8

    stage(0, 0);
    int t = 0;   // global tile counter; parity t&1

    for (int phase = 0; phase < 2; ++phase) {
        const int Qt = phase ? QtB : QtA;
        const int nkt = 2 * Qt + 2;

        bf16x8 aq[2][2];
#pragma unroll
        for (int mi = 0; mi < 2; mi++) {
            int qrow = Qt * 128 + w * 32 + mi * 16 + l16;
#pragma unroll
            for (int kc = 0; kc < 2; kc++)
                aq[mi][kc] = *(const bf16x8*)&Qg[qrow * 64 + kc * 32 + quad * 8];
        }

        f32x4 oacc[2][4] = {};
        f32x4 lacc[2] = {};

        for (int kt = 0; kt < nkt; ++kt, ++t) {
            __syncthreads();   // tile (t&1) ready; prior reads of other buffer drained
            if (kt + 1 < nkt)    stage(kt + 1, (t + 1) & 1);
            else if (phase == 0) stage(0,      (t + 1) & 1);   // bridge to phase B
            const short* kb_cur = &kbuf[t & 1][0];
            const short* vb_cur = &vbuf[t & 1][0];

            // ---- S = Q K^T  (independent chains: 2 mi x 4 nt)
            f32x4 sc[2][4] = {};
            __builtin_amdgcn_s_setprio(1);
#pragma unroll
            for (int nt = 0; nt < 4; nt++) {
                int raddr = (nt * 16 + l16) * 64;
#pragma unroll
                for (int kc = 0; kc < 2; kc++) {
                    bf16x8 kf = *(const bf16x8*)&kb_cur[raddr + (((quad + kc * 4) ^ l7) * 8)];
                    sc[0][nt] = __builtin_amdgcn_mfma_f32_16x16x32_bf16(aq[0][kc], kf, sc[0][nt], 0, 0, 0);
                    sc[1][nt] = __builtin_amdgcn_mfma_f32_16x16x32_bf16(aq[1][kc], kf, sc[1][nt], 0, 0, 0);
                }
            }
            __builtin_amdgcn_s_setprio(0);
            // ---- causal mask (only last two tiles of each phase hit the diagonal)
            if (kt >= nkt - 2) {
#pragma unroll
                for (int mi = 0; mi < 2; mi++)
#pragma unroll
                    for (int nt = 0; nt < 4; nt++)
#pragma unroll
                        for (int r = 0; r < 4; r++) {
                            int col = kt * 64 + nt * 16 + l16;
                            int row = Qt * 128 + w * 32 + mi * 16 + quad * 4 + r;
                            if (col > row) sc[mi][nt][r] = -__builtin_inff();
                        }
            }
            // ---- p = exp2(s); truncated bf16 store (d16_hi, zero VALU convert)
#pragma unroll
            for (int mi = 0; mi < 2; mi++)
#pragma unroll
                for (int nt = 0; nt < 4; nt++)
#pragma unroll
                    for (int r = 0; r < 4; r++) {
                        float pv = __builtin_amdgcn_exp2f(sc[mi][nt][r]);
                        int q = mi * 16 + quad * 4 + r;
                        union { float f; unsigned short us[2]; } uu;
                        uu.f = pv;
                        myp[q * 64 + (((nt * 2 + (l16 >> 3)) ^ (q & 7)) * 8) + l7] =
                            (short)uu.us[1];
                    }
            // ---- P: LDS -> A-frags (in-wave DS ordering; no barrier needed)
            bf16x8 ap[2][2];
#pragma unroll
            for (int mi = 0; mi < 2; mi++)
#pragma unroll
                for (int kc = 0; kc < 2; kc++)
                    ap[mi][kc] = *(const bf16x8*)&myp[(mi * 16 + l16) * 64 +
                                                      (((quad + kc * 4) ^ l7) * 8)];
            // ---- O += P V ; denominator += P * ones (MFMA pipe)
            __builtin_amdgcn_s_setprio(1);
#pragma unroll
            for (int nt = 0; nt < 4; nt++) {
                int raddr = (nt * 16 + l16) * 64;
#pragma unroll
                for (int kc = 0; kc < 2; kc++) {
                    bf16x8 vf = *(const bf16x8*)&vb_cur[raddr + (((quad + kc * 4) ^ l7) * 8)];
                    oacc[0][nt] = __builtin_amdgcn_mfma_f32_16x16x32_bf16(ap[0][kc], vf, oacc[0][nt], 0, 0, 0);
                    oacc[1][nt] = __builtin_amdgcn_mfma_f32_16x16x32_bf16(ap[1][kc], vf, oacc[1][nt], 0, 0, 0);
                }
            }
#pragma unroll
            for (int mi = 0; mi < 2; mi++) {
                lacc[mi] = __builtin_amdgcn_mfma_f32_16x16x32_bf16(ap[mi][0], ones, lacc[mi], 0, 0, 0);
                lacc[mi] = __builtin_amdgcn_mfma_f32_16x16x32_bf16(ap[mi][1], ones, lacc[mi], 0, 0, 0);
            }
            __builtin_amdgcn_s_setprio(0);
        }
        // ---- epilogue: lacc holds per-row denominators (all cols equal)
#pragma unroll
        for (int mi = 0; mi < 2; mi++)
#pragma unroll
            for (int r = 0; r < 4; r++) {
                float inv = 1.0f / lacc[mi][r];
                int srow = Qt * 128 + w * 32 + mi * 16 + quad * 4 + r;
#pragma unroll
                for (int nt = 0; nt < 4; nt++) {
                    int hd = nt * 16 + l16;
                    O[(b * S_LEN + srow) * DMODEL + h * HDIM + hd] = f2bf(oacc[mi][nt][r] * inv);
                }
            }
    }
}

// ---------------------------------------------------------------- launch
extern "C" void kernel_launch(void* const* d_in, const int* in_sizes, int n_in,
                              void* d_out, int out_size, void* d_ws, size_t ws_size,
                              hipStream_t stream) {
    const float* x  = (const float*)d_in[0];
    const int*   tp = (const int*)d_in[1];
    const float* Wq = (const float*)d_in[2];
    const float* Wk = (const float*)d_in[3];
    const float* Wv = (const float*)d_in[4];
    const float* Wo = (const float*)d_in[5];
    float* out = (float*)d_out;

    char* ws = (char*)d_ws;
    const size_t MB = 1024 * 1024;
    short* xb  = (short*)(ws);             // 16 MB: x bf16 [8192][1024]; reused as o_buf
    short* wqb = (short*)(ws + 16 * MB);
    short* wkb = (short*)(ws + 18 * MB);
    short* wvb = (short*)(ws + 20 * MB);
    short* wob = (short*)(ws + 22 * MB);
    short* Qb  = (short*)(ws + 24 * MB);   // 16 MB [BH][S][64]
    short* Kb  = (short*)(ws + 40 * MB);   // 16 MB [BH][S][64]
    short* Vtb = (short*)(ws + 56 * MB);   // 16 MB [BH][64][S]
    // RoPE table (2 MB) lives in d_out: scratch until gemm_o overwrites it.
    float2* tab = (float2*)d_out;

    prep<<<13312, 256, 0, stream>>>(x, Wq, Wk, Wv, Wo, tp,
                                    xb, wqb, wkb, wvb, wob, tab);

    gemm_qkv<<<dim3(24, 32), 512, 0, stream>>>(xb, wqb, wkb, wvb, tab, Qb, Kb, Vtb);

    attn<<<dim3(8, 64), 256, 0, stream>>>(Qb, Kb, Vtb, xb);

    gemm_o<<<dim3(16, 64), 256, 0, stream>>>(xb, wob, out);
}

// Round 9
// 245.368 us; speedup vs baseline: 1.2182x; 1.0105x over previous
//
#include <hip/hip_runtime.h>

// Problem constants: B=4, S=2048, D=1024, H=16, HD=64
#define S_LEN 2048
#define NH 16
#define HDIM 64
#define DMODEL 1024

typedef __attribute__((ext_vector_type(8))) short bf16x8;
typedef __attribute__((ext_vector_type(4))) float f32x4;

__device__ __forceinline__ short f2bf(float f) {
    union { float f; unsigned u; } x; x.f = f;
    unsigned r = x.u + 0x7fffu + ((x.u >> 16) & 1u);  // round-to-nearest-even
    return (short)(r >> 16);
}

#define GLDS(g, l) __builtin_amdgcn_global_load_lds( \
    (__attribute__((address_space(1))) void*)(g),    \
    (__attribute__((address_space(3))) void*)(l), 16, 0, 0)

#define QSCALE 0.18033688011112042f   // 0.125 * log2(e)
#define FREQ_L 0.41524101186109327f   // log2(10000)/32

// ---------------------------------------------------------------- prep (one launch)
__global__ __launch_bounds__(256) void prep(const float* __restrict__ x,
                                            const float* __restrict__ wq,
                                            const float* __restrict__ wk,
                                            const float* __restrict__ wv,
                                            const float* __restrict__ wo,
                                            const int* __restrict__ tp,
                                            short* __restrict__ xb,
                                            short* __restrict__ wqb,
                                            short* __restrict__ wkb,
                                            short* __restrict__ wvb,
                                            short* __restrict__ wob,
                                            float2* __restrict__ tab) {
    int bid = blockIdx.x;
    if (bid < 8192) {
        int i = bid * 256 + threadIdx.x;
        float4 v = ((const float4*)x)[i];
        short4 o;
        o.x = f2bf(v.x); o.y = f2bf(v.y); o.z = f2bf(v.z); o.w = f2bf(v.w);
        ((short4*)xb)[i] = o;
    } else if (bid < 12288) {
        int sel = (bid - 8192) >> 10;
        const float* in = sel == 0 ? wq : sel == 1 ? wk : sel == 2 ? wv : wo;
        short* out = sel == 0 ? wqb : sel == 1 ? wkb : sel == 2 ? wvb : wob;
        int i = ((bid - 8192) & 1023) * 256 + threadIdx.x;
        float4 v = ((const float4*)in)[i];
        short4 o;
        o.x = f2bf(v.x); o.y = f2bf(v.y); o.z = f2bf(v.z); o.w = f2bf(v.w);
        ((short4*)out)[i] = o;
    } else {
        int idx = (bid - 12288) * 256 + threadIdx.x;   // < 262144
        int b = idx >> 16, s = (idx >> 5) & 2047, i = idx & 31;
        float p = (float)tp[(b << 11) + s];
        float freq = exp2f(-(float)i * FREQ_L);
        float sn, cs;
        sincosf(p * freq, &sn, &cs);
        tab[idx] = make_float2(cs, sn);
    }
}

// ---------------------------------------------------------------- fused QKV GEMM + RoPE
// Round-6 version KEPT (71.3 us measured round-8).  Phase-interleaved
// counted-vmcnt schedule, BK=64/phase, 16 phases, 3 slots x 48 KB = 144 KB LDS.
// Proven conflict-free BK=64 addressing.  BM=256, BN=128; 512 threads = 8
// waves (4Mx2N); grid 768 = 3 CU-rounds.
__global__ __launch_bounds__(512) void gemm_qkv(const short* __restrict__ A,
                                                const short* __restrict__ Bq,
                                                const short* __restrict__ Bk,
                                                const short* __restrict__ Bv,
                                                const float2* __restrict__ tab,
                                                short* __restrict__ Qo,
                                                short* __restrict__ Ko,
                                                short* __restrict__ Vo) {
    constexpr int K = 1024;
    __shared__ __align__(16) short smem[3 * 24576];

    const int sel = blockIdx.x >> 3;
    const int bn = blockIdx.x & 7;
    const int bm = blockIdx.y;
    const short* Bm = sel == 0 ? Bq : sel == 1 ? Bk : Bv;
    short* Cb = sel == 0 ? Qo : sel == 1 ? Ko : Vo;

    const int tid = threadIdx.x;
    const int lane = tid & 63;
    const int w = tid >> 6;          // 0..7
    const int wm = w >> 1;           // 0..3  (M-waves)
    const int wn = w & 1;            // 0..1  (N-waves)
    const int quad = lane >> 4, l16 = lane & 15;
    const int l7 = l16 & 7;

    int aoff[4], boff[2];
#pragma unroll
    for (int i = 0; i < 4; i++) {
        int Lc = i * 512 + tid;
        int row = Lc >> 3;
        int cc = (Lc & 7) ^ (row & 7);
        aoff[i] = (bm * 256 + row) * K + cc * 8;
    }
#pragma unroll
    for (int i = 0; i < 2; i++) {
        int Lc = i * 512 + tid;
        int row = Lc >> 3;
        int cc = (Lc & 7) ^ (row & 7);
        boff[i] = (bn * 128 + row) * K + cc * 8;
    }

    auto stage = [&](int h, int slot) {
        char* sbase = (char*)smem + slot * 49152;
        const int kh = h * 64;
#pragma unroll
        for (int i = 0; i < 4; i++)
            GLDS(A + aoff[i] + kh, sbase + i * 8192 + w * 1024);
#pragma unroll
        for (int i = 0; i < 2; i++)
            GLDS(Bm + boff[i] + kh, sbase + 32768 + i * 8192 + w * 1024);
    };

    f32x4 acc[4][4] = {};

    auto compute = [&](int slot) {
        const short* sA = smem + slot * 24576;
        const short* sB = sA + 16384;
#pragma unroll
        for (int kc = 0; kc < 2; kc++) {
            const int c = ((kc * 4 + quad) ^ l7) * 8;
            bf16x8 af[4], bfm[4];
#pragma unroll
            for (int mi = 0; mi < 4; mi++)
                af[mi] = *(const bf16x8*)&sA[(wm * 64 + mi * 16 + l16) * 64 + c];
#pragma unroll
            for (int ni = 0; ni < 4; ni++)
                bfm[ni] = *(const bf16x8*)&sB[(wn * 64 + ni * 16 + l16) * 64 + c];
            __builtin_amdgcn_s_setprio(1);
#pragma unroll
            for (int mi = 0; mi < 4; mi++)
#pragma unroll
                for (int ni = 0; ni < 4; ni++)
                    acc[mi][ni] = __builtin_amdgcn_mfma_f32_16x16x32_bf16(af[mi], bfm[ni],
                                                                          acc[mi][ni], 0, 0, 0);
            __builtin_amdgcn_s_setprio(0);
        }
    };

    stage(0, 0); stage(1, 1);

    auto step = [&](int h, int sc, int ss) {
        asm volatile("s_waitcnt vmcnt(6)" ::: "memory");   // tile h complete
        __builtin_amdgcn_s_barrier();
        __builtin_amdgcn_sched_barrier(0);
        stage(h + 2, ss);
        compute(sc);
    };

    for (int h = 0; h < 12; h += 3) {
        step(h + 0, 0, 2);
        step(h + 1, 1, 0);
        step(h + 2, 2, 1);
    }
    step(12, 0, 2);
    step(13, 1, 0);
    asm volatile("s_waitcnt vmcnt(6)" ::: "memory");
    __builtin_amdgcn_s_barrier();
    __builtin_amdgcn_sched_barrier(0);
    compute(2);
    asm volatile("s_waitcnt vmcnt(0)" ::: "memory");
    __builtin_amdgcn_s_barrier();
    __builtin_amdgcn_sched_barrier(0);
    compute(0);

    const int gm0 = bm * 256 + wm * 64;
    const int gn0 = bn * 128 + wn * 64;

    if (sel == 2) {
        // ---- V^T -> [B][H][64][S] via LDS transpose (re-use staging LDS).
        short* T = smem;
        __syncthreads();
#pragma unroll
        for (int mi = 0; mi < 4; mi++) {
            int lmb = wm * 64 + mi * 16 + quad * 4;
#pragma unroll
            for (int ni = 0; ni < 4; ni++) {
                int ln = wn * 64 + ni * 16 + l16;
                short4 pk;
                pk.x = f2bf(acc[mi][ni][0]);
                pk.y = f2bf(acc[mi][ni][1]);
                pk.z = f2bf(acc[mi][ni][2]);
                pk.w = f2bf(acc[mi][ni][3]);
                *(short4*)&T[ln * 256 + (lmb ^ ((ln & 31) << 3))] = pk;
            }
        }
        __syncthreads();
        const int row = tid >> 2, qt = tid & 3;
        const int grow = bn * 128 + row;
        const int gb = bm >> 3;
        const int gs0 = (bm & 7) * 256;
        short* dst = Cb + (((size_t)(gb * NH + (grow >> 6)) * HDIM + (grow & 63)) * S_LEN
                           + gs0 + qt * 64);
#pragma unroll
        for (int j = 0; j < 8; j++) {
            bf16x8 v = *(const bf16x8*)&T[row * 256 +
                        ((qt * 64 + j * 8) ^ ((row & 31) << 3))];
            *(bf16x8*)(dst + j * 8) = v;
        }
    } else {
        const float qs = (sel == 0) ? QSCALE : 1.0f;
#pragma unroll
        for (int mi = 0; mi < 4; mi++)
#pragma unroll
            for (int r = 0; r < 4; r++) {
                int gm = gm0 + mi * 16 + quad * 4 + r;        // b*2048 + s
                const float2* trow = tab + (gm << 5);
                int b = gm >> 11, s = gm & 2047;
#pragma unroll
                for (int ni = 0; ni < 4; ni++) {
                    float2 cs = trow[ni * 8 + (l16 >> 1)];
                    float v = acc[mi][ni][r];
                    float prt = __shfl_xor(v, 1, 64);
                    float val = (l16 & 1) ? (prt * cs.y + v * cs.x)
                                          : (v * cs.x - prt * cs.y);
                    int gn = gn0 + ni * 16 + l16;
                    int h = gn >> 6, hd = gn & 63;
                    Cb[((b * NH + h) * S_LEN + s) * HDIM + hd] = f2bf(val * qs);
                }
            }
    }
}

// ---------------------------------------------------------------- O-projection GEMM
// Round-1 version KEPT.  128x64 tiles, BK=32, 3-buffer counted-vmcnt pipeline
// (3 loads/tile -> vmcnt(3)), raw s_barrier.  LDS 36 KB.  grid (16, 64).
__global__ __launch_bounds__(256) void gemm_o(const short* __restrict__ A,
                                              const short* __restrict__ Bw,
                                              float* __restrict__ Cf) {
    constexpr int N = 1024, K = 1024, BK = 32;
    __shared__ __align__(16) short sa[3][128 * BK];  // 3 x 8 KB
    __shared__ __align__(16) short sb[3][64 * BK];   // 3 x 4 KB

    const int tid = threadIdx.x;
    const int lane = tid & 63;
    const int w = tid >> 6;
    const int quad = lane >> 4, l16 = lane & 15;
    const int bn = blockIdx.x, bm = blockIdx.y;
    const int arow0 = bm * 128, brow0 = bn * 64;

    int aoff[2], boff;
#pragma unroll
    for (int i = 0; i < 2; i++) {
        int cs = i * 256 + tid;
        int row = cs >> 2;
        int gc = (cs & 3) ^ ((row >> 1) & 3);
        aoff[i] = (arow0 + row) * K + gc * 8;
    }
    {
        int row = tid >> 2;
        int gc = (tid & 3) ^ ((row >> 1) & 3);
        boff = (brow0 + row) * K + gc * 8;
    }

    auto stage = [&](int kt, int b) {
        const int k0 = kt * BK;
#pragma unroll
        for (int i = 0; i < 2; i++)
            GLDS(A + aoff[i] + k0, (char*)&sa[b][0] + i * 4096 + w * 1024);
        GLDS(Bw + boff + k0, (char*)&sb[b][0] + w * 1024);
    };

    f32x4 acc[2][4] = {};
    const int rsw = (quad ^ ((l16 >> 1) & 3)) * 8;

    auto compute = [&](int b) {
        bf16x8 af[2];
#pragma unroll
        for (int mi = 0; mi < 2; mi++)
            af[mi] = *(const bf16x8*)&sa[b][(w * 32 + mi * 16 + l16) * BK + rsw];
#pragma unroll
        for (int ni = 0; ni < 4; ni++) {
            bf16x8 bfr = *(const bf16x8*)&sb[b][(ni * 16 + l16) * BK + rsw];
#pragma unroll
            for (int mi = 0; mi < 2; mi++)
                acc[mi][ni] = __builtin_amdgcn_mfma_f32_16x16x32_bf16(af[mi], bfr,
                                                                     acc[mi][ni], 0, 0, 0);
        }
    };

    stage(0, 0);
    stage(1, 1);

    auto step = [&](int kt, int b, int bs) {
        asm volatile("s_waitcnt vmcnt(3)" ::: "memory");
        __builtin_amdgcn_s_barrier();
        __builtin_amdgcn_sched_barrier(0);
        stage(kt + 2, bs);
        compute(b);
    };

    for (int kt = 0; kt < 30; kt += 3) {
        step(kt + 0, 0, 2);
        step(kt + 1, 1, 0);
        step(kt + 2, 2, 1);
    }
    asm volatile("s_waitcnt vmcnt(3)" ::: "memory");
    __builtin_amdgcn_s_barrier();
    __builtin_amdgcn_sched_barrier(0);
    compute(0);
    asm volatile("s_waitcnt vmcnt(0)" ::: "memory");
    __builtin_amdgcn_s_barrier();
    __builtin_amdgcn_sched_barrier(0);
    compute(1);

    const int gm0 = arow0 + w * 32;
#pragma unroll
    for (int mi = 0; mi < 2; mi++)
#pragma unroll
        for (int ni = 0; ni < 4; ni++)
#pragma unroll
            for (int r = 0; r < 4; r++) {
                int gm = gm0 + mi * 16 + quad * 4 + r;
                int gn = brow0 + ni * 16 + l16;
                Cf[gm * N + gn] = acc[mi][ni][r];
            }
}

// ---------------------------------------------------------------- flash attention (causal)
// Q,K: [BH][S][64] bf16 (Q pre-scaled by 0.125*log2e), Vt: [BH][64][S] bf16,
// O: [B][S][D] bf16.  Fixed-max softmax.
// Round-9: 1-tile SOFTWARE PIPELINE on top of the round-8 paired structure.
// Round-8 counters: all pipes <30% busy at 2 waves/SIMD -> the per-tile chain
// QK^T -> exp2 -> P-store -> P-load -> PV is SERIAL per wave.  Break it:
// at iter t issue QK^T(t) and PV(t-1) back-to-back (independent MFMA chains),
// softmax(t) runs behind them.  P-frags carry across iters in registers —
// TWO NAMED sets (apA/apB) swapped by a 2-wide unrolled loop (nkt = 2Qt+2 is
// always even; rule-#20: no runtime-indexed reg arrays).  K/V now need THREE
// LDS slots (PV reads slot t-1 while stage writes t+1): 3x8+3x8+16 = 64 KB
// -> still 2 blocks/CU (grid 512).  Per-phase drain: one standalone PV after
// the loop.  setprio(1) kept around the merged MFMA cluster.
__global__ __launch_bounds__(256, 2) void attn(const short* __restrict__ Q,
                                               const short* __restrict__ Km,
                                               const short* __restrict__ Vt,
                                               short* __restrict__ O) {
    __shared__ __align__(16) short kbuf[3][64 * 64];   // 24 KB
    __shared__ __align__(16) short vbuf[3][64 * 64];   // 24 KB
    __shared__ __align__(16) short pbuf[4][32 * 64];   // 16 KB (per-wave private)

    const int lane = threadIdx.x & 63;
    const int w = threadIdx.x >> 6;
    const int quad = lane >> 4, l16 = lane & 15;
    const int l7 = l16 & 7;
    const int bh = blockIdx.y;

    const short* Qg = Q  + bh * S_LEN * 64;
    const short* Kg = Km + bh * S_LEN * 64;
    const short* Vg = Vt + bh * 64 * S_LEN;
    short* myp = &pbuf[w][0];

    const int b = bh >> 4, h = bh & 15;

    bf16x8 ones;
#pragma unroll
    for (int j = 0; j < 8; j++) ones[j] = (short)0x3f80;   // bf16 1.0

    auto stage = [&](int kt, int slot) {
        const short* kt_base = Kg + kt * 64 * 64;
        const short* vt_base = Vg + kt * 64;
#pragma unroll
        for (int i = 0; i < 2; ++i) {
            int ch = w * 128 + i * 64 + lane;
            int row = ch >> 3;
            int c = (ch & 7) ^ (row & 7);
            GLDS(kt_base + row * 64 + c * 8, (char*)&kbuf[slot][(w * 128 + i * 64) * 8]);
        }
#pragma unroll
        for (int i = 0; i < 2; ++i) {
            int ch = w * 128 + i * 64 + lane;
            int row = ch >> 3;
            int c = (ch & 7) ^ (row & 7);
            GLDS(vt_base + row * S_LEN + c * 8, (char*)&vbuf[slot][(w * 128 + i * 64) * 8]);
        }
    };

    const int QtA = blockIdx.x;        // 0..7
    const int QtB = 15 - blockIdx.x;   // 15..8

    bf16x8 apA[2][2], apB[2][2];
    int s0 = 0;                        // LDS slot of the next tile to compute
    stage(0, 0);

    for (int phase = 0; phase < 2; ++phase) {
        const int Qt = phase ? QtB : QtA;
        const int nkt = 2 * Qt + 2;    // always even

        bf16x8 aq[2][2];
#pragma unroll
        for (int mi = 0; mi < 2; mi++) {
            int qrow = Qt * 128 + w * 32 + mi * 16 + l16;
#pragma unroll
            for (int kc = 0; kc < 2; kc++)
                aq[mi][kc] = *(const bf16x8*)&Qg[qrow * 64 + kc * 32 + quad * 8];
        }

        f32x4 oacc[2][4] = {};
        f32x4 lacc[2] = {};

        // one pipelined iteration: tile kt computed from slot scur; PV of the
        // PREVIOUS tile (app) from slot sprev; next tile staged into snext;
        // this tile's P lands in apc.
        auto iter = [&](int kt, int scur, int snext, int sprev,
                        bf16x8 (&apc)[2][2], bf16x8 (&app)[2][2], bool hasPrev) {
            __syncthreads();   // tile kt staged; all reads of slot snext done
            int stk = kt + 1;
            if (stk < nkt)       stage(stk, snext);
            else if (phase == 0) stage(0,   snext);   // bridge to phase B
            const short* kb = &kbuf[scur][0];
            const short* vb = &vbuf[sprev][0];

            // ---- QK^T(kt) and PV(kt-1): independent MFMA chains
            f32x4 sc[2][4] = {};
            __builtin_amdgcn_s_setprio(1);
#pragma unroll
            for (int nt = 0; nt < 4; nt++) {
                int raddr = (nt * 16 + l16) * 64;
#pragma unroll
                for (int kc = 0; kc < 2; kc++) {
                    bf16x8 kf = *(const bf16x8*)&kb[raddr + (((quad + kc * 4) ^ l7) * 8)];
                    sc[0][nt] = __builtin_amdgcn_mfma_f32_16x16x32_bf16(aq[0][kc], kf, sc[0][nt], 0, 0, 0);
                    sc[1][nt] = __builtin_amdgcn_mfma_f32_16x16x32_bf16(aq[1][kc], kf, sc[1][nt], 0, 0, 0);
                }
            }
            if (hasPrev) {
#pragma unroll
                for (int nt = 0; nt < 4; nt++) {
                    int raddr = (nt * 16 + l16) * 64;
#pragma unroll
                    for (int kc = 0; kc < 2; kc++) {
                        bf16x8 vf = *(const bf16x8*)&vb[raddr + (((quad + kc * 4) ^ l7) * 8)];
                        oacc[0][nt] = __builtin_amdgcn_mfma_f32_16x16x32_bf16(app[0][kc], vf, oacc[0][nt], 0, 0, 0);
                        oacc[1][nt] = __builtin_amdgcn_mfma_f32_16x16x32_bf16(app[1][kc], vf, oacc[1][nt], 0, 0, 0);
                    }
                }
#pragma unroll
                for (int mi = 0; mi < 2; mi++) {
                    lacc[mi] = __builtin_amdgcn_mfma_f32_16x16x32_bf16(app[mi][0], ones, lacc[mi], 0, 0, 0);
                    lacc[mi] = __builtin_amdgcn_mfma_f32_16x16x32_bf16(app[mi][1], ones, lacc[mi], 0, 0, 0);
                }
            }
            __builtin_amdgcn_s_setprio(0);

            // ---- causal mask (last two tiles only)
            if (kt >= nkt - 2) {
#pragma unroll
                for (int mi = 0; mi < 2; mi++)
#pragma unroll
                    for (int nt = 0; nt < 4; nt++)
#pragma unroll
                        for (int r = 0; r < 4; r++) {
                            int col = kt * 64 + nt * 16 + l16;
                            int row = Qt * 128 + w * 32 + mi * 16 + quad * 4 + r;
                            if (col > row) sc[mi][nt][r] = -__builtin_inff();
                        }
            }
            // ---- p = exp2(s); truncated bf16 store; read back into apc
#pragma unroll
            for (int mi = 0; mi < 2; mi++)
#pragma unroll
                for (int nt = 0; nt < 4; nt++)
#pragma unroll
                    for (int r = 0; r < 4; r++) {
                        float pv = __builtin_amdgcn_exp2f(sc[mi][nt][r]);
                        int q = mi * 16 + quad * 4 + r;
                        union { float f; unsigned short us[2]; } uu;
                        uu.f = pv;
                        myp[q * 64 + (((nt * 2 + (l16 >> 3)) ^ (q & 7)) * 8) + l7] =
                            (short)uu.us[1];
                    }
#pragma unroll
            for (int mi = 0; mi < 2; mi++)
#pragma unroll
                for (int kc = 0; kc < 2; kc++)
                    apc[mi][kc] = *(const bf16x8*)&myp[(mi * 16 + l16) * 64 +
                                                       (((quad + kc * 4) ^ l7) * 8)];
        };

        for (int kt = 0; kt < nkt; kt += 2) {
            int s1 = s0 + 1; if (s1 == 3) s1 = 0;
            int s2 = s1 + 1; if (s2 == 3) s2 = 0;
            iter(kt,     s0, s1, s2, apA, apB, kt > 0);   // prev slot = s0-1 = s2
            iter(kt + 1, s1, s2, s0, apB, apA, true);
            s0 = s2;
        }
        // ---- drain: PV of the last tile (in apB; its V is in slot s0-1)
        {
            int slast = s0 - 1; if (slast < 0) slast = 2;
            const short* vb = &vbuf[slast][0];
            __builtin_amdgcn_s_setprio(1);
#pragma unroll
            for (int nt = 0; nt < 4; nt++) {
                int raddr = (nt * 16 + l16) * 64;
#pragma unroll
                for (int kc = 0; kc < 2; kc++) {
                    bf16x8 vf = *(const bf16x8*)&vb[raddr + (((quad + kc * 4) ^ l7) * 8)];
                    oacc[0][nt] = __builtin_amdgcn_mfma_f32_16x16x32_bf16(apB[0][kc], vf, oacc[0][nt], 0, 0, 0);
                    oacc[1][nt] = __builtin_amdgcn_mfma_f32_16x16x32_bf16(apB[1][kc], vf, oacc[1][nt], 0, 0, 0);
                }
            }
#pragma unroll
            for (int mi = 0; mi < 2; mi++) {
                lacc[mi] = __builtin_amdgcn_mfma_f32_16x16x32_bf16(apB[mi][0], ones, lacc[mi], 0, 0, 0);
                lacc[mi] = __builtin_amdgcn_mfma_f32_16x16x32_bf16(apB[mi][1], ones, lacc[mi], 0, 0, 0);
            }
            __builtin_amdgcn_s_setprio(0);
        }
        // ---- epilogue: lacc holds per-row denominators (all cols equal)
#pragma unroll
        for (int mi = 0; mi < 2; mi++)
#pragma unroll
            for (int r = 0; r < 4; r++) {
                float inv = 1.0f / lacc[mi][r];
                int srow = Qt * 128 + w * 32 + mi * 16 + quad * 4 + r;
#pragma unroll
                for (int nt = 0; nt < 4; nt++) {
                    int hd = nt * 16 + l16;
                    O[(b * S_LEN + srow) * DMODEL + h * HDIM + hd] = f2bf(oacc[mi][nt][r] * inv);
                }
            }
    }
}

// ---------------------------------------------------------------- launch
extern "C" void kernel_launch(void* const* d_in, const int* in_sizes, int n_in,
                              void* d_out, int out_size, void* d_ws, size_t ws_size,
                              hipStream_t stream) {
    const float* x  = (const float*)d_in[0];
    const int*   tp = (const int*)d_in[1];
    const float* Wq = (const float*)d_in[2];
    const float* Wk = (const float*)d_in[3];
    const float* Wv = (const float*)d_in[4];
    const float* Wo = (const float*)d_in[5];
    float* out = (float*)d_out;

    char* ws = (char*)d_ws;
    const size_t MB = 1024 * 1024;
    short* xb  = (short*)(ws);             // 16 MB: x bf16 [8192][1024]; reused as o_buf
    short* wqb = (short*)(ws + 16 * MB);
    short* wkb = (short*)(ws + 18 * MB);
    short* wvb = (short*)(ws + 20 * MB);
    short* wob = (short*)(ws + 22 * MB);
    short* Qb  = (short*)(ws + 24 * MB);   // 16 MB [BH][S][64]
    short* Kb  = (short*)(ws + 40 * MB);   // 16 MB [BH][S][64]
    short* Vtb = (short*)(ws + 56 * MB);   // 16 MB [BH][64][S]
    // RoPE table (2 MB) lives in d_out: scratch until gemm_o overwrites it.
    float2* tab = (float2*)d_out;

    prep<<<13312, 256, 0, stream>>>(x, Wq, Wk, Wv, Wo, tp,
                                    xb, wqb, wkb, wvb, wob, tab);

    gemm_qkv<<<dim3(24, 32), 512, 0, stream>>>(xb, wqb, wkb, wvb, tab, Qb, Kb, Vtb);

    attn<<<dim3(8, 64), 256, 0, stream>>>(Qb, Kb, Vtb, xb);

    gemm_o<<<dim3(16, 64), 256, 0, stream>>>(xb, wob, out);
}

// Round 10
// 228.137 us; speedup vs baseline: 1.3102x; 1.0755x over previous
//
#include <hip/hip_runtime.h>

// Problem constants: B=4, S=2048, D=1024, H=16, HD=64
#define S_LEN 2048
#define NH 16
#define HDIM 64
#define DMODEL 1024

typedef __attribute__((ext_vector_type(8))) short bf16x8;
typedef __attribute__((ext_vector_type(4))) float f32x4;

__device__ __forceinline__ short f2bf(float f) {
    union { float f; unsigned u; } x; x.f = f;
    unsigned r = x.u + 0x7fffu + ((x.u >> 16) & 1u);  // round-to-nearest-even
    return (short)(r >> 16);
}

#define GLDS(g, l) __builtin_amdgcn_global_load_lds( \
    (__attribute__((address_space(1))) void*)(g),    \
    (__attribute__((address_space(3))) void*)(l), 16, 0, 0)

#define QSCALE 0.18033688011112042f   // 0.125 * log2(e)
#define FREQ_L 0.41524101186109327f   // log2(10000)/32

// ---------------------------------------------------------------- prep (one launch)
__global__ __launch_bounds__(256) void prep(const float* __restrict__ x,
                                            const float* __restrict__ wq,
                                            const float* __restrict__ wk,
                                            const float* __restrict__ wv,
                                            const float* __restrict__ wo,
                                            const int* __restrict__ tp,
                                            short* __restrict__ xb,
                                            short* __restrict__ wqb,
                                            short* __restrict__ wkb,
                                            short* __restrict__ wvb,
                                            short* __restrict__ wob,
                                            float2* __restrict__ tab) {
    int bid = blockIdx.x;
    if (bid < 8192) {
        int i = bid * 256 + threadIdx.x;
        float4 v = ((const float4*)x)[i];
        short4 o;
        o.x = f2bf(v.x); o.y = f2bf(v.y); o.z = f2bf(v.z); o.w = f2bf(v.w);
        ((short4*)xb)[i] = o;
    } else if (bid < 12288) {
        int sel = (bid - 8192) >> 10;
        const float* in = sel == 0 ? wq : sel == 1 ? wk : sel == 2 ? wv : wo;
        short* out = sel == 0 ? wqb : sel == 1 ? wkb : sel == 2 ? wvb : wob;
        int i = ((bid - 8192) & 1023) * 256 + threadIdx.x;
        float4 v = ((const float4*)in)[i];
        short4 o;
        o.x = f2bf(v.x); o.y = f2bf(v.y); o.z = f2bf(v.z); o.w = f2bf(v.w);
        ((short4*)out)[i] = o;
    } else {
        int idx = (bid - 12288) * 256 + threadIdx.x;   // < 262144
        int b = idx >> 16, s = (idx >> 5) & 2047, i = idx & 31;
        float p = (float)tp[(b << 11) + s];
        float freq = exp2f(-(float)i * FREQ_L);
        float sn, cs;
        sincosf(p * freq, &sn, &cs);
        tab[idx] = make_float2(cs, sn);
    }
}

// ---------------------------------------------------------------- fused QKV GEMM + RoPE
// Round-10: same 16-phase counted-vmcnt kernel as round-6/8/9 (70.0 us) with
// an XCD-locality grid swap (T1): grid (32,24), bm = blockIdx.x (fastest).
// Position p = y*32+bm -> p%8 = bm%8 (32%8==0), so all 24 blocks sharing an
// A-panel (same bm, all sel/bn) land on ONE XCD; 4 panels/XCD = 2 MB fits L2.
// Round-9 FETCH was 87.5 MB vs ~22 MB unique inputs (A streamed 8x).
__global__ __launch_bounds__(512) void gemm_qkv(const short* __restrict__ A,
                                                const short* __restrict__ Bq,
                                                const short* __restrict__ Bk,
                                                const short* __restrict__ Bv,
                                                const float2* __restrict__ tab,
                                                short* __restrict__ Qo,
                                                short* __restrict__ Ko,
                                                short* __restrict__ Vo) {
    constexpr int K = 1024;
    __shared__ __align__(16) short smem[3 * 24576];

    const int bm = blockIdx.x;               // 0..31  (fastest -> XCD-pinned A)
    const int sel = blockIdx.y >> 3;         // 0..2
    const int bn = blockIdx.y & 7;           // 0..7
    const short* Bm = sel == 0 ? Bq : sel == 1 ? Bk : Bv;
    short* Cb = sel == 0 ? Qo : sel == 1 ? Ko : Vo;

    const int tid = threadIdx.x;
    const int lane = tid & 63;
    const int w = tid >> 6;          // 0..7
    const int wm = w >> 1;           // 0..3  (M-waves)
    const int wn = w & 1;            // 0..1  (N-waves)
    const int quad = lane >> 4, l16 = lane & 15;
    const int l7 = l16 & 7;

    int aoff[4], boff[2];
#pragma unroll
    for (int i = 0; i < 4; i++) {
        int Lc = i * 512 + tid;
        int row = Lc >> 3;
        int cc = (Lc & 7) ^ (row & 7);
        aoff[i] = (bm * 256 + row) * K + cc * 8;
    }
#pragma unroll
    for (int i = 0; i < 2; i++) {
        int Lc = i * 512 + tid;
        int row = Lc >> 3;
        int cc = (Lc & 7) ^ (row & 7);
        boff[i] = (bn * 128 + row) * K + cc * 8;
    }

    auto stage = [&](int h, int slot) {
        char* sbase = (char*)smem + slot * 49152;
        const int kh = h * 64;
#pragma unroll
        for (int i = 0; i < 4; i++)
            GLDS(A + aoff[i] + kh, sbase + i * 8192 + w * 1024);
#pragma unroll
        for (int i = 0; i < 2; i++)
            GLDS(Bm + boff[i] + kh, sbase + 32768 + i * 8192 + w * 1024);
    };

    f32x4 acc[4][4] = {};

    auto compute = [&](int slot) {
        const short* sA = smem + slot * 24576;
        const short* sB = sA + 16384;
#pragma unroll
        for (int kc = 0; kc < 2; kc++) {
            const int c = ((kc * 4 + quad) ^ l7) * 8;
            bf16x8 af[4], bfm[4];
#pragma unroll
            for (int mi = 0; mi < 4; mi++)
                af[mi] = *(const bf16x8*)&sA[(wm * 64 + mi * 16 + l16) * 64 + c];
#pragma unroll
            for (int ni = 0; ni < 4; ni++)
                bfm[ni] = *(const bf16x8*)&sB[(wn * 64 + ni * 16 + l16) * 64 + c];
            __builtin_amdgcn_s_setprio(1);
#pragma unroll
            for (int mi = 0; mi < 4; mi++)
#pragma unroll
                for (int ni = 0; ni < 4; ni++)
                    acc[mi][ni] = __builtin_amdgcn_mfma_f32_16x16x32_bf16(af[mi], bfm[ni],
                                                                          acc[mi][ni], 0, 0, 0);
            __builtin_amdgcn_s_setprio(0);
        }
    };

    stage(0, 0); stage(1, 1);

    auto step = [&](int h, int sc, int ss) {
        asm volatile("s_waitcnt vmcnt(6)" ::: "memory");   // tile h complete
        __builtin_amdgcn_s_barrier();
        __builtin_amdgcn_sched_barrier(0);
        stage(h + 2, ss);
        compute(sc);
    };

    for (int h = 0; h < 12; h += 3) {
        step(h + 0, 0, 2);
        step(h + 1, 1, 0);
        step(h + 2, 2, 1);
    }
    step(12, 0, 2);
    step(13, 1, 0);
    asm volatile("s_waitcnt vmcnt(6)" ::: "memory");
    __builtin_amdgcn_s_barrier();
    __builtin_amdgcn_sched_barrier(0);
    compute(2);
    asm volatile("s_waitcnt vmcnt(0)" ::: "memory");
    __builtin_amdgcn_s_barrier();
    __builtin_amdgcn_sched_barrier(0);
    compute(0);

    const int gm0 = bm * 256 + wm * 64;
    const int gn0 = bn * 128 + wn * 64;

    if (sel == 2) {
        // ---- V^T -> [B][H][64][S] via LDS transpose (re-use staging LDS).
        short* T = smem;
        __syncthreads();
#pragma unroll
        for (int mi = 0; mi < 4; mi++) {
            int lmb = wm * 64 + mi * 16 + quad * 4;
#pragma unroll
            for (int ni = 0; ni < 4; ni++) {
                int ln = wn * 64 + ni * 16 + l16;
                short4 pk;
                pk.x = f2bf(acc[mi][ni][0]);
                pk.y = f2bf(acc[mi][ni][1]);
                pk.z = f2bf(acc[mi][ni][2]);
                pk.w = f2bf(acc[mi][ni][3]);
                *(short4*)&T[ln * 256 + (lmb ^ ((ln & 31) << 3))] = pk;
            }
        }
        __syncthreads();
        const int row = tid >> 2, qt = tid & 3;
        const int grow = bn * 128 + row;
        const int gb = bm >> 3;
        const int gs0 = (bm & 7) * 256;
        short* dst = Cb + (((size_t)(gb * NH + (grow >> 6)) * HDIM + (grow & 63)) * S_LEN
                           + gs0 + qt * 64);
#pragma unroll
        for (int j = 0; j < 8; j++) {
            bf16x8 v = *(const bf16x8*)&T[row * 256 +
                        ((qt * 64 + j * 8) ^ ((row & 31) << 3))];
            *(bf16x8*)(dst + j * 8) = v;
        }
    } else {
        const float qs = (sel == 0) ? QSCALE : 1.0f;
#pragma unroll
        for (int mi = 0; mi < 4; mi++)
#pragma unroll
            for (int r = 0; r < 4; r++) {
                int gm = gm0 + mi * 16 + quad * 4 + r;        // b*2048 + s
                const float2* trow = tab + (gm << 5);
                int b = gm >> 11, s = gm & 2047;
#pragma unroll
                for (int ni = 0; ni < 4; ni++) {
                    float2 cs = trow[ni * 8 + (l16 >> 1)];
                    float v = acc[mi][ni][r];
                    float prt = __shfl_xor(v, 1, 64);
                    float val = (l16 & 1) ? (prt * cs.y + v * cs.x)
                                          : (v * cs.x - prt * cs.y);
                    int gn = gn0 + ni * 16 + l16;
                    int h = gn >> 6, hd = gn & 63;
                    Cb[((b * NH + h) * S_LEN + s) * HDIM + hd] = f2bf(val * qs);
                }
            }
    }
}

// ---------------------------------------------------------------- O-projection GEMM
// Round-10: PORTED to the proven 16-phase counted-vmcnt structure (identical
// loop/staging to gemm_qkv; 51.5 GF ran at 70 us there -> 17.2 GF here should
// be ~23-26 us).  BM=256, BN=128, BK=64/phase, 3 slots x 48 KB = 144 KB LDS,
// 512 threads = 8 waves (4Mx2N).  grid (32,8) = 256 blocks = exactly 1
// CU-round; bm = blockIdx.x fastest -> same-A-panel blocks XCD-pinned
// (p%8 = bm%8), A 2 MB/XCD + full B 2 MB = 4 MB fits L2.
// Epilogue: plain f32 row-major stores.
__global__ __launch_bounds__(512) void gemm_o(const short* __restrict__ A,
                                              const short* __restrict__ Bw,
                                              float* __restrict__ Cf) {
    constexpr int K = 1024, N = 1024;
    __shared__ __align__(16) short smem[3 * 24576];

    const int bm = blockIdx.x;       // 0..31
    const int bn = blockIdx.y;       // 0..7

    const int tid = threadIdx.x;
    const int lane = tid & 63;
    const int w = tid >> 6;          // 0..7
    const int wm = w >> 1;           // 0..3
    const int wn = w & 1;            // 0..1
    const int quad = lane >> 4, l16 = lane & 15;
    const int l7 = l16 & 7;

    int aoff[4], boff[2];
#pragma unroll
    for (int i = 0; i < 4; i++) {
        int Lc = i * 512 + tid;
        int row = Lc >> 3;
        int cc = (Lc & 7) ^ (row & 7);
        aoff[i] = (bm * 256 + row) * K + cc * 8;
    }
#pragma unroll
    for (int i = 0; i < 2; i++) {
        int Lc = i * 512 + tid;
        int row = Lc >> 3;
        int cc = (Lc & 7) ^ (row & 7);
        boff[i] = (bn * 128 + row) * K + cc * 8;
    }

    auto stage = [&](int h, int slot) {
        char* sbase = (char*)smem + slot * 49152;
        const int kh = h * 64;
#pragma unroll
        for (int i = 0; i < 4; i++)
            GLDS(A + aoff[i] + kh, sbase + i * 8192 + w * 1024);
#pragma unroll
        for (int i = 0; i < 2; i++)
            GLDS(Bw + boff[i] + kh, sbase + 32768 + i * 8192 + w * 1024);
    };

    f32x4 acc[4][4] = {};

    auto compute = [&](int slot) {
        const short* sA = smem + slot * 24576;
        const short* sB = sA + 16384;
#pragma unroll
        for (int kc = 0; kc < 2; kc++) {
            const int c = ((kc * 4 + quad) ^ l7) * 8;
            bf16x8 af[4], bfm[4];
#pragma unroll
            for (int mi = 0; mi < 4; mi++)
                af[mi] = *(const bf16x8*)&sA[(wm * 64 + mi * 16 + l16) * 64 + c];
#pragma unroll
            for (int ni = 0; ni < 4; ni++)
                bfm[ni] = *(const bf16x8*)&sB[(wn * 64 + ni * 16 + l16) * 64 + c];
            __builtin_amdgcn_s_setprio(1);
#pragma unroll
            for (int mi = 0; mi < 4; mi++)
#pragma unroll
                for (int ni = 0; ni < 4; ni++)
                    acc[mi][ni] = __builtin_amdgcn_mfma_f32_16x16x32_bf16(af[mi], bfm[ni],
                                                                          acc[mi][ni], 0, 0, 0);
            __builtin_amdgcn_s_setprio(0);
        }
    };

    stage(0, 0); stage(1, 1);

    auto step = [&](int h, int sc, int ss) {
        asm volatile("s_waitcnt vmcnt(6)" ::: "memory");
        __builtin_amdgcn_s_barrier();
        __builtin_amdgcn_sched_barrier(0);
        stage(h + 2, ss);
        compute(sc);
    };

    for (int h = 0; h < 12; h += 3) {
        step(h + 0, 0, 2);
        step(h + 1, 1, 0);
        step(h + 2, 2, 1);
    }
    step(12, 0, 2);
    step(13, 1, 0);
    asm volatile("s_waitcnt vmcnt(6)" ::: "memory");
    __builtin_amdgcn_s_barrier();
    __builtin_amdgcn_sched_barrier(0);
    compute(2);
    asm volatile("s_waitcnt vmcnt(0)" ::: "memory");
    __builtin_amdgcn_s_barrier();
    __builtin_amdgcn_sched_barrier(0);
    compute(0);

    const int gm0 = bm * 256 + wm * 64;
    const int gn0 = bn * 128 + wn * 64;
#pragma unroll
    for (int mi = 0; mi < 4; mi++)
#pragma unroll
        for (int ni = 0; ni < 4; ni++)
#pragma unroll
            for (int r = 0; r < 4; r++) {
                int gm = gm0 + mi * 16 + quad * 4 + r;
                int gn = gn0 + ni * 16 + l16;
                Cf[gm * N + gn] = acc[mi][ni][r];
            }
}

// ---------------------------------------------------------------- flash attention (causal)
// Round-9 pipelined version KEPT, with an XCD-locality grid swap (T1):
// grid (64,8), bh = blockIdx.x (fastest).  Position p = y*64+bh -> p%8 = bh%8,
// so the 8 paired blocks of one bh (sharing that bh's 512 KB K+V) land on ONE
// XCD; 8 bh/XCD -> K/V working set 4 MB = L2.  Round-6 FETCH was 146 MB vs
// 48 MB unique (K/V re-fetched ~3x).
__global__ __launch_bounds__(256, 2) void attn(const short* __restrict__ Q,
                                               const short* __restrict__ Km,
                                               const short* __restrict__ Vt,
                                               short* __restrict__ O) {
    __shared__ __align__(16) short kbuf[3][64 * 64];   // 24 KB
    __shared__ __align__(16) short vbuf[3][64 * 64];   // 24 KB
    __shared__ __align__(16) short pbuf[4][32 * 64];   // 16 KB (per-wave private)

    const int lane = threadIdx.x & 63;
    const int w = threadIdx.x >> 6;
    const int quad = lane >> 4, l16 = lane & 15;
    const int l7 = l16 & 7;
    const int bh = blockIdx.x;         // fastest -> XCD-pinned K/V

    const short* Qg = Q  + bh * S_LEN * 64;
    const short* Kg = Km + bh * S_LEN * 64;
    const short* Vg = Vt + bh * 64 * S_LEN;
    short* myp = &pbuf[w][0];

    const int b = bh >> 4, h = bh & 15;

    bf16x8 ones;
#pragma unroll
    for (int j = 0; j < 8; j++) ones[j] = (short)0x3f80;   // bf16 1.0

    auto stage = [&](int kt, int slot) {
        const short* kt_base = Kg + kt * 64 * 64;
        const short* vt_base = Vg + kt * 64;
#pragma unroll
        for (int i = 0; i < 2; ++i) {
            int ch = w * 128 + i * 64 + lane;
            int row = ch >> 3;
            int c = (ch & 7) ^ (row & 7);
            GLDS(kt_base + row * 64 + c * 8, (char*)&kbuf[slot][(w * 128 + i * 64) * 8]);
        }
#pragma unroll
        for (int i = 0; i < 2; ++i) {
            int ch = w * 128 + i * 64 + lane;
            int row = ch >> 3;
            int c = (ch & 7) ^ (row & 7);
            GLDS(vt_base + row * S_LEN + c * 8, (char*)&vbuf[slot][(w * 128 + i * 64) * 8]);
        }
    };

    const int QtA = blockIdx.y;        // 0..7
    const int QtB = 15 - blockIdx.y;   // 15..8

    bf16x8 apA[2][2], apB[2][2];
    int s0 = 0;                        // LDS slot of the next tile to compute
    stage(0, 0);

    for (int phase = 0; phase < 2; ++phase) {
        const int Qt = phase ? QtB : QtA;
        const int nkt = 2 * Qt + 2;    // always even

        bf16x8 aq[2][2];
#pragma unroll
        for (int mi = 0; mi < 2; mi++) {
            int qrow = Qt * 128 + w * 32 + mi * 16 + l16;
#pragma unroll
            for (int kc = 0; kc < 2; kc++)
                aq[mi][kc] = *(const bf16x8*)&Qg[qrow * 64 + kc * 32 + quad * 8];
        }

        f32x4 oacc[2][4] = {};
        f32x4 lacc[2] = {};

        auto iter = [&](int kt, int scur, int snext, int sprev,
                        bf16x8 (&apc)[2][2], bf16x8 (&app)[2][2], bool hasPrev) {
            __syncthreads();   // tile kt staged; all reads of slot snext done
            int stk = kt + 1;
            if (stk < nkt)       stage(stk, snext);
            else if (phase == 0) stage(0,   snext);   // bridge to phase B
            const short* kb = &kbuf[scur][0];
            const short* vb = &vbuf[sprev][0];

            // ---- QK^T(kt) and PV(kt-1): independent MFMA chains
            f32x4 sc[2][4] = {};
            __builtin_amdgcn_s_setprio(1);
#pragma unroll
            for (int nt = 0; nt < 4; nt++) {
                int raddr = (nt * 16 + l16) * 64;
#pragma unroll
                for (int kc = 0; kc < 2; kc++) {
                    bf16x8 kf = *(const bf16x8*)&kb[raddr + (((quad + kc * 4) ^ l7) * 8)];
                    sc[0][nt] = __builtin_amdgcn_mfma_f32_16x16x32_bf16(aq[0][kc], kf, sc[0][nt], 0, 0, 0);
                    sc[1][nt] = __builtin_amdgcn_mfma_f32_16x16x32_bf16(aq[1][kc], kf, sc[1][nt], 0, 0, 0);
                }
            }
            if (hasPrev) {
#pragma unroll
                for (int nt = 0; nt < 4; nt++) {
                    int raddr = (nt * 16 + l16) * 64;
#pragma unroll
                    for (int kc = 0; kc < 2; kc++) {
                        bf16x8 vf = *(const bf16x8*)&vb[raddr + (((quad + kc * 4) ^ l7) * 8)];
                        oacc[0][nt] = __builtin_amdgcn_mfma_f32_16x16x32_bf16(app[0][kc], vf, oacc[0][nt], 0, 0, 0);
                        oacc[1][nt] = __builtin_amdgcn_mfma_f32_16x16x32_bf16(app[1][kc], vf, oacc[1][nt], 0, 0, 0);
                    }
                }
#pragma unroll
                for (int mi = 0; mi < 2; mi++) {
                    lacc[mi] = __builtin_amdgcn_mfma_f32_16x16x32_bf16(app[mi][0], ones, lacc[mi], 0, 0, 0);
                    lacc[mi] = __builtin_amdgcn_mfma_f32_16x16x32_bf16(app[mi][1], ones, lacc[mi], 0, 0, 0);
                }
            }
            __builtin_amdgcn_s_setprio(0);

            // ---- causal mask (last two tiles only)
            if (kt >= nkt - 2) {
#pragma unroll
                for (int mi = 0; mi < 2; mi++)
#pragma unroll
                    for (int nt = 0; nt < 4; nt++)
#pragma unroll
                        for (int r = 0; r < 4; r++) {
                            int col = kt * 64 + nt * 16 + l16;
                            int row = Qt * 128 + w * 32 + mi * 16 + quad * 4 + r;
                            if (col > row) sc[mi][nt][r] = -__builtin_inff();
                        }
            }
            // ---- p = exp2(s); truncated bf16 store; read back into apc
#pragma unroll
            for (int mi = 0; mi < 2; mi++)
#pragma unroll
                for (int nt = 0; nt < 4; nt++)
#pragma unroll
                    for (int r = 0; r < 4; r++) {
                        float pv = __builtin_amdgcn_exp2f(sc[mi][nt][r]);
                        int q = mi * 16 + quad * 4 + r;
                        union { float f; unsigned short us[2]; } uu;
                        uu.f = pv;
                        myp[q * 64 + (((nt * 2 + (l16 >> 3)) ^ (q & 7)) * 8) + l7] =
                            (short)uu.us[1];
                    }
#pragma unroll
            for (int mi = 0; mi < 2; mi++)
#pragma unroll
                for (int kc = 0; kc < 2; kc++)
                    apc[mi][kc] = *(const bf16x8*)&myp[(mi * 16 + l16) * 64 +
                                                       (((quad + kc * 4) ^ l7) * 8)];
        };

        for (int kt = 0; kt < nkt; kt += 2) {
            int s1 = s0 + 1; if (s1 == 3) s1 = 0;
            int s2 = s1 + 1; if (s2 == 3) s2 = 0;
            iter(kt,     s0, s1, s2, apA, apB, kt > 0);   // prev slot = s0-1 = s2
            iter(kt + 1, s1, s2, s0, apB, apA, true);
            s0 = s2;
        }
        // ---- drain: PV of the last tile (in apB; its V is in slot s0-1)
        {
            int slast = s0 - 1; if (slast < 0) slast = 2;
            const short* vb = &vbuf[slast][0];
            __builtin_amdgcn_s_setprio(1);
#pragma unroll
            for (int nt = 0; nt < 4; nt++) {
                int raddr = (nt * 16 + l16) * 64;
#pragma unroll
                for (int kc = 0; kc < 2; kc++) {
                    bf16x8 vf = *(const bf16x8*)&vb[raddr + (((quad + kc * 4) ^ l7) * 8)];
                    oacc[0][nt] = __builtin_amdgcn_mfma_f32_16x16x32_bf16(apB[0][kc], vf, oacc[0][nt], 0, 0, 0);
                    oacc[1][nt] = __builtin_amdgcn_mfma_f32_16x16x32_bf16(apB[1][kc], vf, oacc[1][nt], 0, 0, 0);
                }
            }
#pragma unroll
            for (int mi = 0; mi < 2; mi++) {
                lacc[mi] = __builtin_amdgcn_mfma_f32_16x16x32_bf16(apB[mi][0], ones, lacc[mi], 0, 0, 0);
                lacc[mi] = __builtin_amdgcn_mfma_f32_16x16x32_bf16(apB[mi][1], ones, lacc[mi], 0, 0, 0);
            }
            __builtin_amdgcn_s_setprio(0);
        }
        // ---- epilogue: lacc holds per-row denominators (all cols equal)
#pragma unroll
        for (int mi = 0; mi < 2; mi++)
#pragma unroll
            for (int r = 0; r < 4; r++) {
                float inv = 1.0f / lacc[mi][r];
                int srow = Qt * 128 + w * 32 + mi * 16 + quad * 4 + r;
#pragma unroll
                for (int nt = 0; nt < 4; nt++) {
                    int hd = nt * 16 + l16;
                    O[(b * S_LEN + srow) * DMODEL + h * HDIM + hd] = f2bf(oacc[mi][nt][r] * inv);
                }
            }
    }
}

// ---------------------------------------------------------------- launch
extern "C" void kernel_launch(void* const* d_in, const int* in_sizes, int n_in,
                              void* d_out, int out_size, void* d_ws, size_t ws_size,
                              hipStream_t stream) {
    const float* x  = (const float*)d_in[0];
    const int*   tp = (const int*)d_in[1];
    const float* Wq = (const float*)d_in[2];
    const float* Wk = (const float*)d_in[3];
    const float* Wv = (const float*)d_in[4];
    const float* Wo = (const float*)d_in[5];
    float* out = (float*)d_out;

    char* ws = (char*)d_ws;
    const size_t MB = 1024 * 1024;
    short* xb  = (short*)(ws);             // 16 MB: x bf16 [8192][1024]; reused as o_buf
    short* wqb = (short*)(ws + 16 * MB);
    short* wkb = (short*)(ws + 18 * MB);
    short* wvb = (short*)(ws + 20 * MB);
    short* wob = (short*)(ws + 22 * MB);
    short* Qb  = (short*)(ws + 24 * MB);   // 16 MB [BH][S][64]
    short* Kb  = (short*)(ws + 40 * MB);   // 16 MB [BH][S][64]
    short* Vtb = (short*)(ws + 56 * MB);   // 16 MB [BH][64][S]
    // RoPE table (2 MB) lives in d_out: scratch until gemm_o overwrites it.
    float2* tab = (float2*)d_out;

    prep<<<13312, 256, 0, stream>>>(x, Wq, Wk, Wv, Wo, tp,
                                    xb, wqb, wkb, wvb, wob, tab);

    gemm_qkv<<<dim3(32, 24), 512, 0, stream>>>(xb, wqb, wkb, wvb, tab, Qb, Kb, Vtb);

    attn<<<dim3(64, 8), 256, 0, stream>>>(Qb, Kb, Vtb, xb);

    gemm_o<<<dim3(32, 8), 512, 0, stream>>>(xb, wob, out);
}